// Round 7
// baseline (273.953 us; speedup 1.0000x reference)
//
#include <hip/hip_runtime.h>
#include <math.h>

#define B_DIM 4
#define C_DIM 256
#define N_DIM 2048
#define H_DIM 8
#define HD    64
#define HB    32                 // H*B
#define NTOK  (B_DIM * N_DIM)    // 8192
#define LOG2E 1.44269504f

typedef __attribute__((ext_vector_type(8))) short bf16x8;
typedef __attribute__((ext_vector_type(4))) float f32x4;

static __device__ __forceinline__ short f2bf(float f) {          // RNE (cold paths)
    unsigned u = __builtin_bit_cast(unsigned, f);
    u += 0x7fffu + ((u >> 16) & 1u);
    return (short)(u >> 16);
}
static __device__ __forceinline__ short f2bf_fast(float f) {     // round-half-up (P>0 hot path)
    unsigned u = __builtin_bit_cast(unsigned, f);
    return (short)((u + 0x8000u) >> 16);
}
static __device__ __forceinline__ float bf2f(short s) {
    unsigned u = ((unsigned)(unsigned short)s) << 16;
    return __builtin_bit_cast(float, u);
}

#define MFMA16(A, Bv, Cv) __builtin_amdgcn_mfma_f32_16x16x32_bf16(A, Bv, Cv, 0, 0, 0)

// Fragment-major layouts (fragment = 64 lanes x 16 B = 1 KB contiguous):
//   QS/KS(hb, rt, ks, lane, j) = M[hb][n = rt*16 + (lane&15)][d = ks*32 + (lane>>4)*8 + j]
//   (QS holds Q * log2e so exp() becomes exp2())
//   VS(hb, nb, ks, dt, lane, j) = Vsc[hb][d = dt*16+(lane&15)][n = nb*64+ks*32+(lane>>4)*8+j]

// ---------------------------------------------------------------------------
// cast+transpose both inputs: z<4 -> x batch z, z>=4 -> y batch z-4
// ---------------------------------------------------------------------------
__global__ __launch_bounds__(256) void cast_transpose_xy(
    const float* __restrict__ X, const float* __restrict__ Y,
    short* __restrict__ Xt, short* __restrict__ Yt)
{
    const int z = blockIdx.z;
    const float* src = (z < 4) ? X : Y;
    short* dst = (z < 4) ? Xt : Yt;
    const int b = z & 3, c0 = blockIdx.y * 64, n0 = blockIdx.x * 64;
    __shared__ float L[64][65];
    const int t = threadIdx.x;
    for (int i = t; i < 4096; i += 256) {
        int cc = i >> 6, nn = i & 63;
        L[cc][nn] = src[((size_t)b * C_DIM + c0 + cc) * N_DIM + n0 + nn];
    }
    __syncthreads();
#pragma unroll
    for (int half = 0; half < 2; ++half) {
        int row = half * 32 + (t >> 3);
        int c8 = (t & 7) * 8;
        bf16x8 o;
#pragma unroll
        for (int j = 0; j < 8; ++j) o[j] = f2bf(L[c8 + j][row]);
        *(bf16x8*)(dst + ((size_t)b * N_DIM + n0 + row) * C_DIM + c0 + c8) = o;
    }
}

// ---------------------------------------------------------------------------
// weights fp32 -> bf16: Wx = Wq (512x256); Wy = [Wk; Wv; Wp] (1088x256)
// ---------------------------------------------------------------------------
__global__ __launch_bounds__(256) void cast_weights(
    const float* __restrict__ Wq, const float* __restrict__ Wk,
    const float* __restrict__ Wv, const float* __restrict__ Wp,
    short* __restrict__ Wx, short* __restrict__ Wy)
{
    const int NW = 512 * C_DIM;  // 131072
    int fid = (blockIdx.x * 256 + threadIdx.x) * 8;
    const float* src; short* dst;
    if (fid < NW) { src = Wq + fid; dst = Wx + fid; }
    else {
        int g = fid - NW;
        dst = Wy + g;
        if (g < NW) src = Wk + g;
        else if (g < 2 * NW) src = Wv + (g - NW);
        else src = Wp + (g - 2 * NW);
    }
    bf16x8 o;
#pragma unroll
    for (int j = 0; j < 8; ++j) o[j] = f2bf(src[j]);
    *(bf16x8*)dst = o;
}

// ---------------------------------------------------------------------------
// Merged MFMA projection. blockIdx.y<8: Q = (Wq x + bq)*log2e.
// blockIdx.y>=8 over Wy/Yt: o<512 -> K; o<1024 -> Vt (hb,d,n); else YP fp32.
// ---------------------------------------------------------------------------
__global__ __launch_bounds__(256) void proj_all(
    const short* __restrict__ Wx, const short* __restrict__ Wyb,
    const short* __restrict__ Xt, const short* __restrict__ Yt,
    const float* __restrict__ bq, const float* __restrict__ bk,
    const float* __restrict__ bv,
    short* __restrict__ Qo, short* __restrict__ Ko,
    short* __restrict__ Vo, float* __restrict__ Yo)
{
    const int oy = blockIdx.y;
    const bool isq = oy < 8;
    const short* Wb = isq ? Wx : Wyb;
    const short* Xb = isq ? Xt : Yt;
    const int o0 = (isq ? oy : oy - 8) * 64;
    const int tok0 = blockIdx.x * 128;
    const int t = threadIdx.x, wave = t >> 6, lane = t & 63;
    const int lo = lane & 15, quad = lane >> 4;

    const short* wbase = Wb + (size_t)(o0 + wave * 16 + lo) * C_DIM + quad * 8;
    const short* xbase = Xb + (size_t)tok0 * C_DIM + quad * 8;

    f32x4 acc[8];
#pragma unroll
    for (int i = 0; i < 8; ++i) acc[i] = (f32x4){0.f, 0.f, 0.f, 0.f};

#pragma unroll 2
    for (int c0 = 0; c0 < C_DIM; c0 += 32) {
        bf16x8 a = *(const bf16x8*)(wbase + c0);
#pragma unroll
        for (int nt = 0; nt < 8; ++nt) {
            bf16x8 bx = *(const bf16x8*)(xbase + (size_t)(nt * 16 + lo) * C_DIM + c0);
            acc[nt] = MFMA16(a, bx, acc[nt]);
        }
    }

#pragma unroll
    for (int r = 0; r < 4; ++r) {
        const int o = o0 + wave * 16 + quad * 4 + r;
        float bval;
        if (isq) bval = bq[o];
        else if (o < 512) bval = bk[o];
        else if (o < 1024) bval = bv[o - 512];
        else bval = 0.f;
#pragma unroll
        for (int nt = 0; nt < 8; ++nt) {
            int tok = tok0 + nt * 16 + lo;
            int b = tok >> 11, n = tok & (N_DIM - 1);
            float v = acc[nt][r] + bval;
            if (isq) {
                int h = o >> 6, d = o & 63;
                Qo[(((size_t)h * B_DIM + b) * N_DIM + n) * HD + d] = f2bf(v * LOG2E);
            } else if (o < 512) {
                int h = o >> 6, d = o & 63;
                Ko[(((size_t)h * B_DIM + b) * N_DIM + n) * HD + d] = f2bf(v);
            } else if (o < 1024) {
                int op = o - 512, h = op >> 6, d = op & 63;
                Vo[(((size_t)h * B_DIM + b) * HD + d) * N_DIM + n] = f2bf(v);
            } else {
                Yo[((size_t)b * N_DIM + n) * HD + (o - 1024)] = v;
            }
        }
    }
}

// ---------------------------------------------------------------------------
// (hb,n,d) bf16 -> fragment-major, for Q then K (one launch, 4096 blocks)
// ---------------------------------------------------------------------------
__global__ __launch_bounds__(256) void qk_swizzle2(
    const short* __restrict__ Qb, const short* __restrict__ Kb,
    short* __restrict__ QS, short* __restrict__ KS)
{
    int tt = blockIdx.x * 256 + threadIdx.x;    // 0..1048575
    int which = tt >> 19;
    int t = tt & 524287;
    const short* src = which ? Kb : Qb;
    short* dst = which ? KS : QS;
    int lane = t & 63, fidx = t >> 6;
    int ks = fidx & 1, rt = (fidx >> 1) & 127, hb = fidx >> 8;
    int lo = lane & 15, quad = lane >> 4;
    const short* sp = src + (size_t)(hb * N_DIM + rt * 16 + lo) * HD + ks * 32 + quad * 8;
    *(bf16x8*)(dst + (size_t)t * 8) = *(const bf16x8*)sp;
}

// ---------------------------------------------------------------------------
// Vt (hb,d,n) bf16 * SC -> fragment-major VS
// ---------------------------------------------------------------------------
__global__ __launch_bounds__(256) void v_swizzle_scale(
    const short* __restrict__ Vt, const float* __restrict__ SC,
    short* __restrict__ VS)
{
    int t = blockIdx.x * 256 + threadIdx.x;     // 0..524287
    int lane = t & 63, fidx = t >> 6;
    int dt = fidx & 3, ks = (fidx >> 2) & 1, nb = (fidx >> 3) & 31, hb = fidx >> 8;
    int lo = lane & 15, quad = lane >> 4;
    int n = nb * 64 + ks * 32 + quad * 8;
    bf16x8 v = *(const bf16x8*)(Vt + (size_t)(hb * HD + dt * 16 + lo) * N_DIM + n);
    const float* sp = SC + (size_t)hb * N_DIM + n;
    bf16x8 o;
#pragma unroll
    for (int j = 0; j < 8; ++j) o[j] = f2bf(bf2f(v[j]) * sp[j]);
    *(bf16x8*)(VS + (size_t)t * 8) = o;
}

// ---------------------------------------------------------------------------
// rowsum: SC[hb][n] = 1 / sum_m exp2(Q'[n].K[m]). 64 n-rows/block (wave=16),
// full m sweep. Coalesced fragment loads; no LDS, no barriers.
// ---------------------------------------------------------------------------
__global__ __launch_bounds__(256, 4) void rowsum_mfma(
    const short* __restrict__ QS, const short* __restrict__ KS,
    float* __restrict__ SC)
{
    const int id = blockIdx.x;
    const int hb = ((id & 7) << 2) | ((id >> 3) & 3);
    const int n0 = (id >> 5) * 64;
    const int t = threadIdx.x, wave = t >> 6, lane = t & 63;
    const int lo = lane & 15, quad = lane >> 4;

    const int rt = (n0 >> 4) + wave;
    bf16x8 a0 = *(const bf16x8*)(QS + ((size_t)(hb * 128 + rt) * 2 + 0) * 512 + lane * 8);
    bf16x8 a1 = *(const bf16x8*)(QS + ((size_t)(hb * 128 + rt) * 2 + 1) * 512 + lane * 8);

    float sm[4] = {0.f, 0.f, 0.f, 0.f};

    for (int m0 = 0; m0 < N_DIM; m0 += 64) {
#pragma unroll
        for (int mt = 0; mt < 4; ++mt) {
            int rtk = (m0 >> 4) + mt;
            bf16x8 b0 = *(const bf16x8*)(KS + ((size_t)(hb * 128 + rtk) * 2 + 0) * 512 + lane * 8);
            bf16x8 b1 = *(const bf16x8*)(KS + ((size_t)(hb * 128 + rtk) * 2 + 1) * 512 + lane * 8);
            f32x4 c = {0.f, 0.f, 0.f, 0.f};
            c = MFMA16(a0, b0, c);
            c = MFMA16(a1, b1, c);
#pragma unroll
            for (int r = 0; r < 4; ++r) sm[r] += exp2f(c[r]);
        }
    }

#pragma unroll
    for (int sft = 1; sft < 16; sft <<= 1)
#pragma unroll
        for (int r = 0; r < 4; ++r) sm[r] += __shfl_xor(sm[r], sft);

    if (lo == 0) {
        int row = n0 + wave * 16 + quad * 4;
#pragma unroll
        for (int r = 0; r < 4; ++r)
            SC[(size_t)hb * N_DIM + row + r] = 1.f / sm[r];
    }
}

// ---------------------------------------------------------------------------
// attnout: out[m,d] = (g * sum_n exp2(Q'[n].K[m]) Vsc[n,d] + YP[m,d]) / (1+g)
// 64-m tile x full n (1024 blocks). Coalesced fragment loads; P via
// XOR-swizzled per-wave LDS rows; main loop barrier-free.
// ---------------------------------------------------------------------------
__global__ __launch_bounds__(256, 4) void attnout_mfma(
    const short* __restrict__ QS, const short* __restrict__ KS,
    const short* __restrict__ VS, const float* __restrict__ YP,
    const float* __restrict__ gamma, float* __restrict__ out)
{
    const int id = blockIdx.x;
    const int hb = ((id & 7) << 2) | ((id >> 3) & 3);
    const int m0 = (id >> 5) * 64;
    const int h = hb >> 2, b = hb & 3;

    __shared__ short Pl[64 * 64];   // [m_local][n_local], 8-short chunks XOR-swizzled

    const int t = threadIdx.x, wave = t >> 6, lane = t & 63;
    const int lo = lane & 15, quad = lane >> 4;

    const int rtm = (m0 >> 4) + wave;
    const bf16x8 bk0 = *(const bf16x8*)(KS + ((size_t)(hb * 128 + rtm) * 2 + 0) * 512 + lane * 8);
    const bf16x8 bk1 = *(const bf16x8*)(KS + ((size_t)(hb * 128 + rtm) * 2 + 1) * 512 + lane * 8);

    f32x4 oacc[4];
#pragma unroll
    for (int dt = 0; dt < 4; ++dt) oacc[dt] = (f32x4){0.f, 0.f, 0.f, 0.f};

    const int row = wave * 16 + lo;        // m_local; row&7 == lo&7
    short* prow = Pl + row * 64;

    for (int n0 = 0; n0 < N_DIM; n0 += 64) {
        // ---- QK -> P = exp2(E'), unnormalized (1/rowsum folded into VS) ----
#pragma unroll
        for (int nt = 0; nt < 4; ++nt) {
            int rt = (n0 >> 4) + nt;
            bf16x8 a0 = *(const bf16x8*)(QS + ((size_t)(hb * 128 + rt) * 2 + 0) * 512 + lane * 8);
            bf16x8 a1 = *(const bf16x8*)(QS + ((size_t)(hb * 128 + rt) * 2 + 1) * 512 + lane * 8);
            f32x4 c = {0.f, 0.f, 0.f, 0.f};
            c = MFMA16(a0, bk0, c);
            c = MFMA16(a1, bk1, c);
            short4 pk;
            pk.x = f2bf_fast(exp2f(c[0]));
            pk.y = f2bf_fast(exp2f(c[1]));
            pk.z = f2bf_fast(exp2f(c[2]));
            pk.w = f2bf_fast(exp2f(c[3]));
            int chunk = nt * 2 + (quad >> 1);
            *(short4*)(prow + (((chunk ^ (lo & 7)) << 3) | ((quad & 1) << 2))) = pk;
        }
        // ---- PV ----
        int nb = n0 >> 6;
#pragma unroll
        for (int ks = 0; ks < 2; ++ks) {
            bf16x8 ap = *(const bf16x8*)(prow + (((ks * 4 + quad) ^ (lo & 7)) << 3));
#pragma unroll
            for (int dt = 0; dt < 4; ++dt) {
                bf16x8 bv = *(const bf16x8*)(
                    VS + ((size_t)(((hb * 32 + nb) * 2 + ks) * 4 + dt) * 64 + lane) * 8);
                oacc[dt] = MFMA16(ap, bv, oacc[dt]);
            }
        }
    }

    const float g = gamma[h];
    const float inv = 1.f / (1.f + g);
#pragma unroll
    for (int dt = 0; dt < 4; ++dt) {
        int d = dt * 16 + lo;
#pragma unroll
        for (int r = 0; r < 4; ++r) {
            int m = m0 + wave * 16 + quad * 4 + r;
            out[((size_t)hb * N_DIM + m) * HD + d] =
                (g * oacc[dt][r] + YP[((size_t)b * N_DIM + m) * HD + d]) * inv;
        }
    }
}

// ---------------------------------------------------------------------------
extern "C" void kernel_launch(void* const* d_in, const int* in_sizes, int n_in,
                              void* d_out, int out_size, void* d_ws, size_t ws_size,
                              hipStream_t stream) {
    const float* x     = (const float*)d_in[0];
    const float* y     = (const float*)d_in[1];
    const float* Wq    = (const float*)d_in[2];
    const float* bq    = (const float*)d_in[3];
    const float* Wk    = (const float*)d_in[4];
    const float* bk    = (const float*)d_in[5];
    const float* Wv    = (const float*)d_in[6];
    const float* bv    = (const float*)d_in[7];
    const float* Wp    = (const float*)d_in[8];
    const float* gamma = (const float*)d_in[9];
    float* out = (float*)d_out;

    const size_t XEL  = (size_t)B_DIM * C_DIM * N_DIM;  // 2,097,152
    const size_t QKV  = (size_t)HB * N_DIM * HD;        // 4,194,304

    short* Xt  = (short*)d_ws;
    short* Yt  = Xt + XEL;
    short* Wx  = Yt + XEL;            // 512*256
    short* Wy  = Wx + 512 * C_DIM;    // 1088*256
    short* Qb  = Wy + 1088 * C_DIM;
    short* Kb  = Qb + QKV;
    short* Vt  = Kb + QKV;
    short* KS  = Vt + QKV;
    short* VS  = KS + QKV;
    float* YPb = (float*)(VS + QKV);
    float* SC  = YPb + (size_t)B_DIM * N_DIM * HD;
    short* QS  = (short*)d_ws;        // overlays Xt+Yt (dead after projections)

    dim3 blk(256);
    cast_transpose_xy<<<dim3(N_DIM / 64, C_DIM / 64, 8), blk, 0, stream>>>(x, y, Xt, Yt);
    cast_weights<<<dim3(200), blk, 0, stream>>>(Wq, Wk, Wv, Wp, Wx, Wy);

    proj_all<<<dim3(NTOK / 128, 25), blk, 0, stream>>>(
        Wx, Wy, Xt, Yt, bq, bk, bv, Qb, Kb, Vt, YPb);

    qk_swizzle2<<<dim3(4096), blk, 0, stream>>>(Qb, Kb, QS, KS);

    rowsum_mfma<<<dim3(1024), blk, 0, stream>>>(QS, KS, SC);
    v_swizzle_scale<<<dim3(2048), blk, 0, stream>>>(Vt, SC, VS);
    attnout_mfma<<<dim3(1024), blk, 0, stream>>>(QS, KS, VS, YPb, gamma, out);
}

// Round 8
// 271.022 us; speedup vs baseline: 1.0108x; 1.0108x over previous
//
#include <hip/hip_runtime.h>
#include <math.h>

#define B_DIM 4
#define C_DIM 256
#define N_DIM 2048
#define H_DIM 8
#define HD    64
#define HB    32                 // H*B
#define NTOK  (B_DIM * N_DIM)    // 8192
#define LOG2E 1.44269504f

typedef __attribute__((ext_vector_type(8))) short bf16x8;
typedef __attribute__((ext_vector_type(4))) float f32x4;

static __device__ __forceinline__ short f2bf(float f) {          // RNE (cold paths)
    unsigned u = __builtin_bit_cast(unsigned, f);
    u += 0x7fffu + ((u >> 16) & 1u);
    return (short)(u >> 16);
}
static __device__ __forceinline__ short f2bf_fast(float f) {     // round-half-up (P>0 hot path)
    unsigned u = __builtin_bit_cast(unsigned, f);
    return (short)((u + 0x8000u) >> 16);
}
static __device__ __forceinline__ float bf2f(short s) {
    unsigned u = ((unsigned)(unsigned short)s) << 16;
    return __builtin_bit_cast(float, u);
}

#define MFMA16(A, Bv, Cv) __builtin_amdgcn_mfma_f32_16x16x32_bf16(A, Bv, Cv, 0, 0, 0)

// Fragment-major layouts (fragment = 64 lanes x 16 B = 1 KB contiguous):
//   QS/KS(hb, rt, ks, lane, j) = M[hb][n = rt*16 + (lane&15)][d = ks*32 + (lane>>4)*8 + j]
//   (QS holds Q * log2e so exp() becomes exp2())
//   VS(hb, nb, ks, dt, lane, j) = Vsc[hb][d = dt*16+(lane&15)][n = nb*64+ks*32+(lane>>4)*8+j]

// ---------------------------------------------------------------------------
// cast+transpose both inputs: z<4 -> x batch z, z>=4 -> y batch z-4
// ---------------------------------------------------------------------------
__global__ __launch_bounds__(256) void cast_transpose_xy(
    const float* __restrict__ X, const float* __restrict__ Y,
    short* __restrict__ Xt, short* __restrict__ Yt)
{
    const int z = blockIdx.z;
    const float* src = (z < 4) ? X : Y;
    short* dst = (z < 4) ? Xt : Yt;
    const int b = z & 3, c0 = blockIdx.y * 64, n0 = blockIdx.x * 64;
    __shared__ float L[64][65];
    const int t = threadIdx.x;
    for (int i = t; i < 4096; i += 256) {
        int cc = i >> 6, nn = i & 63;
        L[cc][nn] = src[((size_t)b * C_DIM + c0 + cc) * N_DIM + n0 + nn];
    }
    __syncthreads();
#pragma unroll
    for (int half = 0; half < 2; ++half) {
        int row = half * 32 + (t >> 3);
        int c8 = (t & 7) * 8;
        bf16x8 o;
#pragma unroll
        for (int j = 0; j < 8; ++j) o[j] = f2bf(L[c8 + j][row]);
        *(bf16x8*)(dst + ((size_t)b * N_DIM + n0 + row) * C_DIM + c0 + c8) = o;
    }
}

// ---------------------------------------------------------------------------
// weights fp32 -> bf16: Wx = Wq (512x256); Wy = [Wk; Wv; Wp] (1088x256)
// ---------------------------------------------------------------------------
__global__ __launch_bounds__(256) void cast_weights(
    const float* __restrict__ Wq, const float* __restrict__ Wk,
    const float* __restrict__ Wv, const float* __restrict__ Wp,
    short* __restrict__ Wx, short* __restrict__ Wy)
{
    const int NW = 512 * C_DIM;  // 131072
    int fid = (blockIdx.x * 256 + threadIdx.x) * 8;
    const float* src; short* dst;
    if (fid < NW) { src = Wq + fid; dst = Wx + fid; }
    else {
        int g = fid - NW;
        dst = Wy + g;
        if (g < NW) src = Wk + g;
        else if (g < 2 * NW) src = Wv + (g - NW);
        else src = Wp + (g - 2 * NW);
    }
    bf16x8 o;
#pragma unroll
    for (int j = 0; j < 8; ++j) o[j] = f2bf(src[j]);
    *(bf16x8*)dst = o;
}

// ---------------------------------------------------------------------------
// Merged MFMA projection. blockIdx.y<8: Q = (Wq x + bq)*log2e.
// blockIdx.y>=8 over Wy/Yt: o<512 -> K; o<1024 -> Vt (hb,d,n); else YP fp32.
// ---------------------------------------------------------------------------
__global__ __launch_bounds__(256) void proj_all(
    const short* __restrict__ Wx, const short* __restrict__ Wyb,
    const short* __restrict__ Xt, const short* __restrict__ Yt,
    const float* __restrict__ bq, const float* __restrict__ bk,
    const float* __restrict__ bv,
    short* __restrict__ Qo, short* __restrict__ Ko,
    short* __restrict__ Vo, float* __restrict__ Yo)
{
    const int oy = blockIdx.y;
    const bool isq = oy < 8;
    const short* Wb = isq ? Wx : Wyb;
    const short* Xb = isq ? Xt : Yt;
    const int o0 = (isq ? oy : oy - 8) * 64;
    const int tok0 = blockIdx.x * 128;
    const int t = threadIdx.x, wave = t >> 6, lane = t & 63;
    const int lo = lane & 15, quad = lane >> 4;

    const short* wbase = Wb + (size_t)(o0 + wave * 16 + lo) * C_DIM + quad * 8;
    const short* xbase = Xb + (size_t)tok0 * C_DIM + quad * 8;

    f32x4 acc[8];
#pragma unroll
    for (int i = 0; i < 8; ++i) acc[i] = (f32x4){0.f, 0.f, 0.f, 0.f};

#pragma unroll 2
    for (int c0 = 0; c0 < C_DIM; c0 += 32) {
        bf16x8 a = *(const bf16x8*)(wbase + c0);
#pragma unroll
        for (int nt = 0; nt < 8; ++nt) {
            bf16x8 bx = *(const bf16x8*)(xbase + (size_t)(nt * 16 + lo) * C_DIM + c0);
            acc[nt] = MFMA16(a, bx, acc[nt]);
        }
    }

#pragma unroll
    for (int r = 0; r < 4; ++r) {
        const int o = o0 + wave * 16 + quad * 4 + r;
        float bval;
        if (isq) bval = bq[o];
        else if (o < 512) bval = bk[o];
        else if (o < 1024) bval = bv[o - 512];
        else bval = 0.f;
#pragma unroll
        for (int nt = 0; nt < 8; ++nt) {
            int tok = tok0 + nt * 16 + lo;
            int b = tok >> 11, n = tok & (N_DIM - 1);
            float v = acc[nt][r] + bval;
            if (isq) {
                int h = o >> 6, d = o & 63;
                Qo[(((size_t)h * B_DIM + b) * N_DIM + n) * HD + d] = f2bf(v * LOG2E);
            } else if (o < 512) {
                int h = o >> 6, d = o & 63;
                Ko[(((size_t)h * B_DIM + b) * N_DIM + n) * HD + d] = f2bf(v);
            } else if (o < 1024) {
                int op = o - 512, h = op >> 6, d = op & 63;
                Vo[(((size_t)h * B_DIM + b) * HD + d) * N_DIM + n] = f2bf(v);
            } else {
                Yo[((size_t)b * N_DIM + n) * HD + (o - 1024)] = v;
            }
        }
    }
}

// ---------------------------------------------------------------------------
// (hb,n,d) bf16 -> fragment-major, for Q then K (one launch, 4096 blocks)
// ---------------------------------------------------------------------------
__global__ __launch_bounds__(256) void qk_swizzle2(
    const short* __restrict__ Qb, const short* __restrict__ Kb,
    short* __restrict__ QS, short* __restrict__ KS)
{
    int tt = blockIdx.x * 256 + threadIdx.x;    // 0..1048575
    int which = tt >> 19;
    int t = tt & 524287;
    const short* src = which ? Kb : Qb;
    short* dst = which ? KS : QS;
    int lane = t & 63, fidx = t >> 6;
    int ks = fidx & 1, rt = (fidx >> 1) & 127, hb = fidx >> 8;
    int lo = lane & 15, quad = lane >> 4;
    const short* sp = src + (size_t)(hb * N_DIM + rt * 16 + lo) * HD + ks * 32 + quad * 8;
    *(bf16x8*)(dst + (size_t)t * 8) = *(const bf16x8*)sp;
}

// ---------------------------------------------------------------------------
// rowsum partials: RSp[z][hb][n] = sum over m-half z of exp2(Q'[n].K[m]).
// 128 n-rows/block (round-6 intensity), m-half per z. 1024 blocks.
// ---------------------------------------------------------------------------
__global__ __launch_bounds__(256, 4) void rowsum_mfma(
    const short* __restrict__ QS, const short* __restrict__ KS,
    float* __restrict__ RSp)
{
    const int id = blockIdx.x;
    const int hb = ((id & 7) << 2) | ((id >> 3) & 3);
    const int z = (id >> 5) & 1;
    const int n0 = (id >> 6) * 128;
    const int mbeg = z * (N_DIM / 2);
    const int t = threadIdx.x, wave = t >> 6, lane = t & 63;
    const int lo = lane & 15, quad = lane >> 4;

    bf16x8 a0[2], a1[2];
#pragma unroll
    for (int s = 0; s < 2; ++s) {
        int rt = (n0 >> 4) + s * 4 + wave;
        a0[s] = *(const bf16x8*)(QS + ((size_t)(hb * 128 + rt) * 2 + 0) * 512 + lane * 8);
        a1[s] = *(const bf16x8*)(QS + ((size_t)(hb * 128 + rt) * 2 + 1) * 512 + lane * 8);
    }

    float sm[2][4];
#pragma unroll
    for (int s = 0; s < 2; ++s)
#pragma unroll
        for (int r = 0; r < 4; ++r) sm[s][r] = 0.f;

    for (int m0 = mbeg; m0 < mbeg + N_DIM / 2; m0 += 64) {
#pragma unroll
        for (int mt = 0; mt < 4; ++mt) {
            int rtk = (m0 >> 4) + mt;
            bf16x8 b0 = *(const bf16x8*)(KS + ((size_t)(hb * 128 + rtk) * 2 + 0) * 512 + lane * 8);
            bf16x8 b1 = *(const bf16x8*)(KS + ((size_t)(hb * 128 + rtk) * 2 + 1) * 512 + lane * 8);
#pragma unroll
            for (int s = 0; s < 2; ++s) {
                f32x4 c = {0.f, 0.f, 0.f, 0.f};
                c = MFMA16(a0[s], b0, c);
                c = MFMA16(a1[s], b1, c);
#pragma unroll
                for (int r = 0; r < 4; ++r) sm[s][r] += exp2f(c[r]);
            }
        }
    }

#pragma unroll
    for (int sft = 1; sft < 16; sft <<= 1)
#pragma unroll
        for (int s = 0; s < 2; ++s)
#pragma unroll
            for (int r = 0; r < 4; ++r) sm[s][r] += __shfl_xor(sm[s][r], sft);

    if (lo == 0) {
#pragma unroll
        for (int s = 0; s < 2; ++s) {
            int row = n0 + s * 64 + wave * 16 + quad * 4;
#pragma unroll
            for (int r = 0; r < 4; ++r)
                RSp[((size_t)z * HB + hb) * N_DIM + row + r] = sm[s][r];
        }
    }
}

// ---------------------------------------------------------------------------
// Vt (hb,d,n) bf16 -> fragment-major VS, scaled by 1/(RSp0[n]+RSp1[n])
// ---------------------------------------------------------------------------
__global__ __launch_bounds__(256) void v_swizzle_scale(
    const short* __restrict__ Vt, const float* __restrict__ RSp,
    short* __restrict__ VS)
{
    int t = blockIdx.x * 256 + threadIdx.x;     // 0..524287
    int lane = t & 63, fidx = t >> 6;
    int dt = fidx & 3, ks = (fidx >> 2) & 1, nb = (fidx >> 3) & 31, hb = fidx >> 8;
    int lo = lane & 15, quad = lane >> 4;
    int n = nb * 64 + ks * 32 + quad * 8;
    bf16x8 v = *(const bf16x8*)(Vt + (size_t)(hb * HD + dt * 16 + lo) * N_DIM + n);
    const float* r0 = RSp + (size_t)hb * N_DIM + n;
    const float* r1 = r0 + (size_t)HB * N_DIM;
    bf16x8 o;
#pragma unroll
    for (int j = 0; j < 8; ++j) o[j] = f2bf(bf2f(v[j]) / (r0[j] + r1[j]));
    *(bf16x8*)(VS + (size_t)t * 8) = o;
}

// ---------------------------------------------------------------------------
// out[h,b,n,d] = YP[b,n,d] / (1 + gamma[h]); attn partials atomic-added later
// ---------------------------------------------------------------------------
__global__ __launch_bounds__(256) void init_out(
    const float* __restrict__ YP, const float* __restrict__ gamma,
    float* __restrict__ out)
{
    size_t flat = ((size_t)blockIdx.x * 256 + threadIdx.x) * 4;
    int d  = flat & 63;
    int n  = (flat >> 6) & (N_DIM - 1);
    int hb = (int)(flat >> 17);
    int h = hb >> 2, b = hb & 3;
    float inv = 1.f / (1.f + gamma[h]);
    float4 yp = *(const float4*)(YP + ((size_t)b * N_DIM + n) * HD + d);
    yp.x *= inv; yp.y *= inv; yp.z *= inv; yp.w *= inv;
    *(float4*)(out + flat) = yp;
}

// ---------------------------------------------------------------------------
// attnout: out[m,d] += g/(1+g) * sum_{n in half} exp2(Q'[n].K[m]) Vsc[n,d]
// 128-m tile (round-6 intensity) x n-half (z). 1024 blocks, 4/CU.
// Coalesced fragment loads; P via XOR-swizzled per-wave LDS; no barriers.
// ---------------------------------------------------------------------------
__global__ __launch_bounds__(256, 4) void attnout_mfma(
    const short* __restrict__ QS, const short* __restrict__ KS,
    const short* __restrict__ VS,
    const float* __restrict__ gamma, float* __restrict__ out)
{
    const int id = blockIdx.x;
    const int hb = ((id & 7) << 2) | ((id >> 3) & 3);
    const int z = (id >> 5) & 1;
    const int m0 = (id >> 6) * 128;
    const int h = hb >> 2;
    const int nbeg = z * (N_DIM / 2);

    __shared__ short Pl[128 * 64];   // [m_local][n_local/8 chunks], XOR-swizzled

    const int t = threadIdx.x, wave = t >> 6, lane = t & 63;
    const int lo = lane & 15, quad = lane >> 4;

    bf16x8 bk0[2], bk1[2];
#pragma unroll
    for (int s = 0; s < 2; ++s) {
        int rt = (m0 >> 4) + s * 4 + wave;
        bk0[s] = *(const bf16x8*)(KS + ((size_t)(hb * 128 + rt) * 2 + 0) * 512 + lane * 8);
        bk1[s] = *(const bf16x8*)(KS + ((size_t)(hb * 128 + rt) * 2 + 1) * 512 + lane * 8);
    }

    f32x4 oacc[2][4];
#pragma unroll
    for (int s = 0; s < 2; ++s)
#pragma unroll
        for (int dt = 0; dt < 4; ++dt) oacc[s][dt] = (f32x4){0.f, 0.f, 0.f, 0.f};

    for (int n0 = nbeg; n0 < nbeg + N_DIM / 2; n0 += 64) {
        // ---- QK -> P = exp2(E'), unnormalized (1/rowsum folded into VS) ----
#pragma unroll
        for (int nt = 0; nt < 4; ++nt) {
            int rt = (n0 >> 4) + nt;
            bf16x8 a0 = *(const bf16x8*)(QS + ((size_t)(hb * 128 + rt) * 2 + 0) * 512 + lane * 8);
            bf16x8 a1 = *(const bf16x8*)(QS + ((size_t)(hb * 128 + rt) * 2 + 1) * 512 + lane * 8);
#pragma unroll
            for (int s = 0; s < 2; ++s) {
                f32x4 c = {0.f, 0.f, 0.f, 0.f};
                c = MFMA16(a0, bk0[s], c);
                c = MFMA16(a1, bk1[s], c);
                short4 pk;
                pk.x = f2bf_fast(exp2f(c[0]));
                pk.y = f2bf_fast(exp2f(c[1]));
                pk.z = f2bf_fast(exp2f(c[2]));
                pk.w = f2bf_fast(exp2f(c[3]));
                int row = s * 64 + wave * 16 + lo;          // row&7 == lo&7
                int chunk = nt * 2 + (quad >> 1);           // (n_local/8) within 64-n slab
                *(short4*)(Pl + row * 64 + (((chunk ^ (lo & 7)) << 3) | ((quad & 1) << 2))) = pk;
            }
        }
        // ---- PV ----
        int nb = n0 >> 6;
#pragma unroll
        for (int ks = 0; ks < 2; ++ks) {
            bf16x8 ap[2];
#pragma unroll
            for (int s = 0; s < 2; ++s) {
                int row = s * 64 + wave * 16 + lo;
                ap[s] = *(const bf16x8*)(Pl + row * 64 + (((ks * 4 + quad) ^ (lo & 7)) << 3));
            }
#pragma unroll
            for (int dt = 0; dt < 4; ++dt) {
                bf16x8 bv = *(const bf16x8*)(
                    VS + ((size_t)(((hb * 32 + nb) * 2 + ks) * 4 + dt) * 64 + lane) * 8);
                oacc[0][dt] = MFMA16(ap[0], bv, oacc[0][dt]);
                oacc[1][dt] = MFMA16(ap[1], bv, oacc[1][dt]);
            }
        }
    }

    const float g = gamma[h];
    const float ginv = g / (1.f + g);
#pragma unroll
    for (int s = 0; s < 2; ++s)
#pragma unroll
        for (int dt = 0; dt < 4; ++dt) {
            int d = dt * 16 + lo;
#pragma unroll
            for (int r = 0; r < 4; ++r) {
                int m = m0 + s * 64 + wave * 16 + quad * 4 + r;
                atomicAdd(&out[((size_t)hb * N_DIM + m) * HD + d], ginv * oacc[s][dt][r]);
            }
        }
}

// ---------------------------------------------------------------------------
extern "C" void kernel_launch(void* const* d_in, const int* in_sizes, int n_in,
                              void* d_out, int out_size, void* d_ws, size_t ws_size,
                              hipStream_t stream) {
    const float* x     = (const float*)d_in[0];
    const float* y     = (const float*)d_in[1];
    const float* Wq    = (const float*)d_in[2];
    const float* bq    = (const float*)d_in[3];
    const float* Wk    = (const float*)d_in[4];
    const float* bk    = (const float*)d_in[5];
    const float* Wv    = (const float*)d_in[6];
    const float* bv    = (const float*)d_in[7];
    const float* Wp    = (const float*)d_in[8];
    const float* gamma = (const float*)d_in[9];
    float* out = (float*)d_out;

    const size_t XEL  = (size_t)B_DIM * C_DIM * N_DIM;  // 2,097,152
    const size_t QKV  = (size_t)HB * N_DIM * HD;        // 4,194,304

    short* Xt  = (short*)d_ws;
    short* Yt  = Xt + XEL;
    short* Wx  = Yt + XEL;            // 512*256
    short* Wy  = Wx + 512 * C_DIM;    // 1088*256
    short* Qb  = Wy + 1088 * C_DIM;
    short* Kb  = Qb + QKV;
    short* Vt  = Kb + QKV;
    short* KS  = Vt + QKV;
    short* VS  = KS + QKV;
    float* YPb = (float*)(VS + QKV);
    float* RSp = YPb + (size_t)B_DIM * N_DIM * HD;      // 2 * HB * N
    short* QS  = (short*)d_ws;        // overlays Xt+Yt (dead after projections)

    dim3 blk(256);
    cast_transpose_xy<<<dim3(N_DIM / 64, C_DIM / 64, 8), blk, 0, stream>>>(x, y, Xt, Yt);
    cast_weights<<<dim3(200), blk, 0, stream>>>(Wq, Wk, Wv, Wp, Wx, Wy);

    proj_all<<<dim3(NTOK / 128, 25), blk, 0, stream>>>(
        Wx, Wy, Xt, Yt, bq, bk, bv, Qb, Kb, Vt, YPb);

    qk_swizzle2<<<dim3(4096), blk, 0, stream>>>(Qb, Kb, QS, KS);

    rowsum_mfma<<<dim3(1024), blk, 0, stream>>>(QS, KS, RSp);
    v_swizzle_scale<<<dim3(2048), blk, 0, stream>>>(Vt, RSp, VS);
    init_out<<<dim3(4096), blk, 0, stream>>>(YPb, gamma, out);
    attnout_mfma<<<dim3(1024), blk, 0, stream>>>(QS, KS, VS, gamma, out);
}

// Round 9
// 224.103 us; speedup vs baseline: 1.2224x; 1.2094x over previous
//
#include <hip/hip_runtime.h>
#include <math.h>

#define B_DIM 4
#define C_DIM 256
#define N_DIM 2048
#define H_DIM 8
#define HD    64
#define HB    32                 // H*B
#define NTOK  (B_DIM * N_DIM)    // 8192
#define LOG2E 1.44269504f

typedef __attribute__((ext_vector_type(8))) short bf16x8;
typedef __attribute__((ext_vector_type(4))) float f32x4;

static __device__ __forceinline__ short f2bf(float f) {          // RNE (cold paths)
    unsigned u = __builtin_bit_cast(unsigned, f);
    u += 0x7fffu + ((u >> 16) & 1u);
    return (short)(u >> 16);
}
static __device__ __forceinline__ short f2bf_fast(float f) {     // round-half-up (P>0 hot path)
    unsigned u = __builtin_bit_cast(unsigned, f);
    return (short)((u + 0x8000u) >> 16);
}
static __device__ __forceinline__ float bf2f(short s) {
    unsigned u = ((unsigned)(unsigned short)s) << 16;
    return __builtin_bit_cast(float, u);
}

#define MFMA16(A, Bv, Cv) __builtin_amdgcn_mfma_f32_16x16x32_bf16(A, Bv, Cv, 0, 0, 0)

// Fragment-major layouts (fragment = 64 lanes x 16 B = 1 KB contiguous):
//   QS/KS(hb, rt, ks, lane, j) = M[hb][n = rt*16 + (lane&15)][d = ks*32 + (lane>>4)*8 + j]
//   (QS holds Q * log2e so exp() becomes exp2())
//   VS(hb, nb, ks, dt, lane, j) = V[hb][d = dt*16+(lane&15)][n = nb*64+ks*32+(lane>>4)*8+j]
//   XS/YS(rt, ks, lane, j) = X[tok = rt*16+(lane&15)][c = ks*32+(lane>>4)*8+j]   (rt = tok>>4 over b-major tokens)
//   WS(ot, ks, lane, j)    = W[o  = ot*16+(lane&15)][c = ks*32+(lane>>4)*8+j]

// ---------------------------------------------------------------------------
// cast+transpose to fragment-major: z<4 -> x batch z, z>=4 -> y batch z-4
// ---------------------------------------------------------------------------
__global__ __launch_bounds__(256) void cast_transpose_xy(
    const float* __restrict__ X, const float* __restrict__ Y,
    short* __restrict__ XS, short* __restrict__ YS)
{
    const int z = blockIdx.z;
    const float* src = (z < 4) ? X : Y;
    short* dst = (z < 4) ? XS : YS;
    const int b = z & 3, c0 = blockIdx.y * 64, n0 = blockIdx.x * 64;
    __shared__ float L[64][65];   // [c_local][n_local]
    const int t = threadIdx.x;
    for (int i = t; i < 4096; i += 256) {
        int cc = i >> 6, nn = i & 63;
        L[cc][nn] = src[((size_t)b * C_DIM + c0 + cc) * N_DIM + n0 + nn];
    }
    __syncthreads();
#pragma unroll
    for (int half = 0; half < 2; ++half) {
        int cid = half * 256 + t;
        int lane = cid & 63, fi = cid >> 6;      // fi 0..7
        int ksl = fi & 1, rtl = fi >> 1;         // rtl 0..3
        int lo = lane & 15, quad = lane >> 4;
        bf16x8 o;
#pragma unroll
        for (int j = 0; j < 8; ++j) o[j] = f2bf(L[ksl * 32 + quad * 8 + j][rtl * 16 + lo]);
        int rt = b * 128 + (n0 >> 4) + rtl;
        int ks = (c0 >> 5) + ksl;
        *(bf16x8*)(dst + ((size_t)(rt * 8 + ks) * 64 + lane) * 8) = o;
    }
}

// ---------------------------------------------------------------------------
// weights fp32 -> bf16 fragment-major: WSx = Wq (32 ot); WSy = [Wk;Wv;Wp] (68 ot)
// ---------------------------------------------------------------------------
__global__ __launch_bounds__(256) void cast_weights(
    const float* __restrict__ Wq, const float* __restrict__ Wk,
    const float* __restrict__ Wv, const float* __restrict__ Wp,
    short* __restrict__ WSx, short* __restrict__ WSy)
{
    int gid = blockIdx.x * 256 + threadIdx.x;   // 0..51199
    int lane = gid & 63, chunk = gid >> 6;      // chunk 0..799
    int lo = lane & 15, quad = lane >> 4;
    const float* src; short* dst;
    if (chunk < 256) {                           // Wq -> WSx
        int ot = chunk >> 3, ks = chunk & 7;
        src = Wq + (size_t)(ot * 16 + lo) * C_DIM + ks * 32 + quad * 8;
        dst = WSx + (size_t)chunk * 512 + lane * 8;
    } else {                                     // Wk|Wv|Wp -> WSy
        int ch = chunk - 256;
        int ot = ch >> 3, ks = ch & 7;
        int row = ot * 16 + lo;
        const float* base = (row < 512) ? (Wk + (size_t)row * C_DIM)
                          : (row < 1024) ? (Wv + (size_t)(row - 512) * C_DIM)
                                         : (Wp + (size_t)(row - 1024) * C_DIM);
        src = base + ks * 32 + quad * 8;
        dst = WSy + (size_t)ch * 512 + lane * 8;
    }
    bf16x8 o;
#pragma unroll
    for (int j = 0; j < 8; ++j) o[j] = f2bf(src[j]);
    *(bf16x8*)dst = o;
}

// ---------------------------------------------------------------------------
// Merged MFMA projection, all loads coalesced fragment loads.
// oy<8: Q=(Wq x + bq)*log2e -> QS. oy 8..15: K -> KS. oy 16..23: V -> VSu.
// oy==24: YP fp32 (b,n,d). Epilogue: LDS transpose -> coalesced 16B stores.
// ---------------------------------------------------------------------------
__global__ __launch_bounds__(256) void proj_all(
    const short* __restrict__ WSx, const short* __restrict__ WSy,
    const short* __restrict__ XS, const short* __restrict__ YS,
    const float* __restrict__ bq, const float* __restrict__ bk,
    const float* __restrict__ bv,
    short* __restrict__ QS, short* __restrict__ KS,
    short* __restrict__ VSu, float* __restrict__ Yo)
{
    const int oy = blockIdx.y;
    const bool isq = oy < 8;
    const short* WS = isq ? WSx : WSy;
    const short* Xs = isq ? XS : YS;
    const int oyl = isq ? oy : oy - 8;
    const int o0 = oyl * 64;
    const int tok0 = blockIdx.x * 128;
    const int t = threadIdx.x, wave = t >> 6, lane = t & 63;
    const int lo = lane & 15, quad = lane >> 4;

    __shared__ __align__(16) char smem[34816];

    const int ot = oyl * 4 + wave;
    const int rt0 = tok0 >> 4;

    f32x4 acc[8];
#pragma unroll
    for (int i = 0; i < 8; ++i) acc[i] = (f32x4){0.f, 0.f, 0.f, 0.f};

#pragma unroll 2
    for (int ks = 0; ks < 8; ++ks) {
        bf16x8 a = *(const bf16x8*)(WS + ((size_t)(ot * 8 + ks) * 64 + lane) * 8);
#pragma unroll
        for (int nt = 0; nt < 8; ++nt) {
            bf16x8 bx = *(const bf16x8*)(Xs + ((size_t)((rt0 + nt) * 8 + ks) * 64 + lane) * 8);
            acc[nt] = MFMA16(a, bx, acc[nt]);
        }
    }

    const int b = tok0 >> 11;
    const int n0b = tok0 & (N_DIM - 1);

    if (oy < 16) {
        // ---- Q or K: T[128][72] bf16 -> fragment-major QS/KS ----
        short* T = (short*)smem;
        const float* bias = isq ? bq : bk;
        const float scale = isq ? LOG2E : 1.f;
        float bvr[4];
#pragma unroll
        for (int r = 0; r < 4; ++r) bvr[r] = bias[o0 + wave * 16 + quad * 4 + r];
#pragma unroll
        for (int nt = 0; nt < 8; ++nt) {
            short4 pk;
            pk.x = f2bf((acc[nt][0] + bvr[0]) * scale);
            pk.y = f2bf((acc[nt][1] + bvr[1]) * scale);
            pk.z = f2bf((acc[nt][2] + bvr[2]) * scale);
            pk.w = f2bf((acc[nt][3] + bvr[3]) * scale);
            *(short4*)(T + (nt * 16 + lo) * 72 + wave * 16 + quad * 4) = pk;
        }
        __syncthreads();
        const int h = oyl;                        // head index (Q: oy, K: oy-8)
        const int hb = h * 4 + b;
        short* dst = isq ? QS : KS;
#pragma unroll
        for (int s = 0; s < 4; ++s) {
            int cid = s * 256 + t;
            int ln = cid & 63, fi = cid >> 6;     // fi 0..15
            int ksd = fi & 1, rtl = fi >> 1;      // rtl 0..7
            bf16x8 v = *(const bf16x8*)(T + (rtl * 16 + (ln & 15)) * 72 + ksd * 32 + (ln >> 4) * 8);
            *(bf16x8*)(dst + (((size_t)(hb * 128 + (n0b >> 4) + rtl) * 2 + ksd) * 512 + ln * 8)) = v;
        }
    } else if (oy < 24) {
        // ---- V: T2[64][136] bf16 -> fragment-major VSu ----
        short* T2 = (short*)smem;
        float bvr[4];
#pragma unroll
        for (int r = 0; r < 4; ++r) bvr[r] = bv[o0 - 512 + wave * 16 + quad * 4 + r];
#pragma unroll
        for (int nt = 0; nt < 8; ++nt)
#pragma unroll
            for (int r = 0; r < 4; ++r) {
                int ol = wave * 16 + quad * 4 + r;
                T2[ol * 136 + nt * 16 + lo] = f2bf(acc[nt][r] + bvr[r]);
            }
        __syncthreads();
        const int h = oy - 16;
        const int hb = h * 4 + b;
#pragma unroll
        for (int s = 0; s < 4; ++s) {
            int cid = s * 256 + t;
            int ln = cid & 63, fi = cid >> 6;     // fi 0..15
            int dt = fi & 3, ksd = (fi >> 2) & 1, nbl = fi >> 3;
            int dl = dt * 16 + (ln & 15);
            int tkl = nbl * 64 + ksd * 32 + (ln >> 4) * 8;
            bf16x8 v = *(const bf16x8*)(T2 + dl * 136 + tkl);
            int nbg = (n0b >> 6) + nbl;
            *(bf16x8*)(VSu + ((size_t)(((hb * 32 + nbg) * 2 + ksd) * 4 + dt) * 64 + ln) * 8) = v;
        }
    } else {
        // ---- YP: T3[128][68] fp32 -> (b,n,d) float4 stores ----
        float* T3 = (float*)smem;
#pragma unroll
        for (int nt = 0; nt < 8; ++nt) {
            float4 f;
            f.x = acc[nt][0]; f.y = acc[nt][1]; f.z = acc[nt][2]; f.w = acc[nt][3];
            *(float4*)(T3 + (nt * 16 + lo) * 68 + wave * 16 + quad * 4) = f;
        }
        __syncthreads();
#pragma unroll
        for (int s = 0; s < 8; ++s) {
            int cid = s * 256 + t;
            int row = cid >> 4, c4 = (cid & 15) * 4;
            float4 f = *(const float4*)(T3 + row * 68 + c4);
            *(float4*)(Yo + ((size_t)(tok0 + row)) * 64 + c4) = f;
        }
    }
}

// ---------------------------------------------------------------------------
// rowsum partials: RSp[z][hb][n] = sum over m-half z of exp2(Q'[n].K[m]).
// 128 n-rows/block, m-half per z. 1024 blocks.
// ---------------------------------------------------------------------------
__global__ __launch_bounds__(256, 4) void rowsum_mfma(
    const short* __restrict__ QS, const short* __restrict__ KS,
    float* __restrict__ RSp)
{
    const int id = blockIdx.x;
    const int hb = ((id & 7) << 2) | ((id >> 3) & 3);
    const int z = (id >> 5) & 1;
    const int n0 = (id >> 6) * 128;
    const int mbeg = z * (N_DIM / 2);
    const int t = threadIdx.x, wave = t >> 6, lane = t & 63;
    const int lo = lane & 15, quad = lane >> 4;

    bf16x8 a0[2], a1[2];
#pragma unroll
    for (int s = 0; s < 2; ++s) {
        int rt = (n0 >> 4) + s * 4 + wave;
        a0[s] = *(const bf16x8*)(QS + ((size_t)(hb * 128 + rt) * 2 + 0) * 512 + lane * 8);
        a1[s] = *(const bf16x8*)(QS + ((size_t)(hb * 128 + rt) * 2 + 1) * 512 + lane * 8);
    }

    float sm[2][4];
#pragma unroll
    for (int s = 0; s < 2; ++s)
#pragma unroll
        for (int r = 0; r < 4; ++r) sm[s][r] = 0.f;

    for (int m0 = mbeg; m0 < mbeg + N_DIM / 2; m0 += 64) {
#pragma unroll
        for (int mt = 0; mt < 4; ++mt) {
            int rtk = (m0 >> 4) + mt;
            bf16x8 b0 = *(const bf16x8*)(KS + ((size_t)(hb * 128 + rtk) * 2 + 0) * 512 + lane * 8);
            bf16x8 b1 = *(const bf16x8*)(KS + ((size_t)(hb * 128 + rtk) * 2 + 1) * 512 + lane * 8);
#pragma unroll
            for (int s = 0; s < 2; ++s) {
                f32x4 c = {0.f, 0.f, 0.f, 0.f};
                c = MFMA16(a0[s], b0, c);
                c = MFMA16(a1[s], b1, c);
#pragma unroll
                for (int r = 0; r < 4; ++r) sm[s][r] += exp2f(c[r]);
            }
        }
    }

#pragma unroll
    for (int sft = 1; sft < 16; sft <<= 1)
#pragma unroll
        for (int s = 0; s < 2; ++s)
#pragma unroll
            for (int r = 0; r < 4; ++r) sm[s][r] += __shfl_xor(sm[s][r], sft);

    if (lo == 0) {
#pragma unroll
        for (int s = 0; s < 2; ++s) {
            int row = n0 + s * 64 + wave * 16 + quad * 4;
#pragma unroll
            for (int r = 0; r < 4; ++r)
                RSp[((size_t)z * HB + hb) * N_DIM + row + r] = sm[s][r];
        }
    }
}

// ---------------------------------------------------------------------------
// VS = VSu * 1/(RSp0[n]+RSp1[n]) — same fragment-major layout in and out
// ---------------------------------------------------------------------------
__global__ __launch_bounds__(256) void v_scale(
    const short* __restrict__ VSu, const float* __restrict__ RSp,
    short* __restrict__ VS)
{
    int t = blockIdx.x * 256 + threadIdx.x;     // 0..524287
    int lane = t & 63, fidx = t >> 6;
    int ks = (fidx >> 2) & 1, nb = (fidx >> 3) & 31, hb = fidx >> 8;
    int n = nb * 64 + ks * 32 + (lane >> 4) * 8;
    bf16x8 v = *(const bf16x8*)(VSu + (size_t)t * 8);
    const float* r0 = RSp + (size_t)hb * N_DIM + n;
    const float* r1 = r0 + (size_t)HB * N_DIM;
    bf16x8 o;
#pragma unroll
    for (int j = 0; j < 8; ++j) o[j] = f2bf(bf2f(v[j]) / (r0[j] + r1[j]));
    *(bf16x8*)(VS + (size_t)t * 8) = o;
}

// ---------------------------------------------------------------------------
// out[h,b,n,d] = YP[b,n,d] / (1 + gamma[h]); attn partials atomic-added later
// ---------------------------------------------------------------------------
__global__ __launch_bounds__(256) void init_out(
    const float* __restrict__ YP, const float* __restrict__ gamma,
    float* __restrict__ out)
{
    size_t flat = ((size_t)blockIdx.x * 256 + threadIdx.x) * 4;
    int d  = flat & 63;
    int n  = (flat >> 6) & (N_DIM - 1);
    int hb = (int)(flat >> 17);
    int h = hb >> 2, b = hb & 3;
    float inv = 1.f / (1.f + gamma[h]);
    float4 yp = *(const float4*)(YP + ((size_t)b * N_DIM + n) * HD + d);
    yp.x *= inv; yp.y *= inv; yp.z *= inv; yp.w *= inv;
    *(float4*)(out + flat) = yp;
}

// ---------------------------------------------------------------------------
// attnout: out[m,d] += g/(1+g) * sum_{n in half} exp2(Q'[n].K[m]) Vsc[n,d]
// 128-m tile x n-half. 1024 blocks. Coalesced fragment loads; P via
// XOR-swizzled per-wave LDS; no barriers in main loop.
// ---------------------------------------------------------------------------
__global__ __launch_bounds__(256, 4) void attnout_mfma(
    const short* __restrict__ QS, const short* __restrict__ KS,
    const short* __restrict__ VS,
    const float* __restrict__ gamma, float* __restrict__ out)
{
    const int id = blockIdx.x;
    const int hb = ((id & 7) << 2) | ((id >> 3) & 3);
    const int z = (id >> 5) & 1;
    const int m0 = (id >> 6) * 128;
    const int h = hb >> 2;
    const int nbeg = z * (N_DIM / 2);

    __shared__ short Pl[128 * 64];   // [m_local][n_local/8 chunks], XOR-swizzled

    const int t = threadIdx.x, wave = t >> 6, lane = t & 63;
    const int lo = lane & 15, quad = lane >> 4;

    bf16x8 bk0[2], bk1[2];
#pragma unroll
    for (int s = 0; s < 2; ++s) {
        int rt = (m0 >> 4) + s * 4 + wave;
        bk0[s] = *(const bf16x8*)(KS + ((size_t)(hb * 128 + rt) * 2 + 0) * 512 + lane * 8);
        bk1[s] = *(const bf16x8*)(KS + ((size_t)(hb * 128 + rt) * 2 + 1) * 512 + lane * 8);
    }

    f32x4 oacc[2][4];
#pragma unroll
    for (int s = 0; s < 2; ++s)
#pragma unroll
        for (int dt = 0; dt < 4; ++dt) oacc[s][dt] = (f32x4){0.f, 0.f, 0.f, 0.f};

    for (int n0 = nbeg; n0 < nbeg + N_DIM / 2; n0 += 64) {
        // ---- QK -> P = exp2(E'), unnormalized (1/rowsum folded into VS) ----
#pragma unroll
        for (int nt = 0; nt < 4; ++nt) {
            int rt = (n0 >> 4) + nt;
            bf16x8 a0 = *(const bf16x8*)(QS + ((size_t)(hb * 128 + rt) * 2 + 0) * 512 + lane * 8);
            bf16x8 a1 = *(const bf16x8*)(QS + ((size_t)(hb * 128 + rt) * 2 + 1) * 512 + lane * 8);
#pragma unroll
            for (int s = 0; s < 2; ++s) {
                f32x4 c = {0.f, 0.f, 0.f, 0.f};
                c = MFMA16(a0, bk0[s], c);
                c = MFMA16(a1, bk1[s], c);
                short4 pk;
                pk.x = f2bf_fast(exp2f(c[0]));
                pk.y = f2bf_fast(exp2f(c[1]));
                pk.z = f2bf_fast(exp2f(c[2]));
                pk.w = f2bf_fast(exp2f(c[3]));
                int row = s * 64 + wave * 16 + lo;          // row&7 == lo&7
                int chunk = nt * 2 + (quad >> 1);
                *(short4*)(Pl + row * 64 + (((chunk ^ (lo & 7)) << 3) | ((quad & 1) << 2))) = pk;
            }
        }
        // ---- PV ----
        int nb = n0 >> 6;
#pragma unroll
        for (int ks = 0; ks < 2; ++ks) {
            bf16x8 ap[2];
#pragma unroll
            for (int s = 0; s < 2; ++s) {
                int row = s * 64 + wave * 16 + lo;
                ap[s] = *(const bf16x8*)(Pl + row * 64 + (((ks * 4 + quad) ^ (lo & 7)) << 3));
            }
#pragma unroll
            for (int dt = 0; dt < 4; ++dt) {
                bf16x8 bv = *(const bf16x8*)(
                    VS + ((size_t)(((hb * 32 + nb) * 2 + ks) * 4 + dt) * 64 + lane) * 8);
                oacc[0][dt] = MFMA16(ap[0], bv, oacc[0][dt]);
                oacc[1][dt] = MFMA16(ap[1], bv, oacc[1][dt]);
            }
        }
    }

    const float g = gamma[h];
    const float ginv = g / (1.f + g);
#pragma unroll
    for (int s = 0; s < 2; ++s)
#pragma unroll
        for (int dt = 0; dt < 4; ++dt) {
            int d = dt * 16 + lo;
#pragma unroll
            for (int r = 0; r < 4; ++r) {
                int m = m0 + s * 64 + wave * 16 + quad * 4 + r;
                atomicAdd(&out[((size_t)hb * N_DIM + m) * HD + d], ginv * oacc[s][dt][r]);
            }
        }
}

// ---------------------------------------------------------------------------
extern "C" void kernel_launch(void* const* d_in, const int* in_sizes, int n_in,
                              void* d_out, int out_size, void* d_ws, size_t ws_size,
                              hipStream_t stream) {
    const float* x     = (const float*)d_in[0];
    const float* y     = (const float*)d_in[1];
    const float* Wq    = (const float*)d_in[2];
    const float* bq    = (const float*)d_in[3];
    const float* Wk    = (const float*)d_in[4];
    const float* bk    = (const float*)d_in[5];
    const float* Wv    = (const float*)d_in[6];
    const float* bv    = (const float*)d_in[7];
    const float* Wp    = (const float*)d_in[8];
    const float* gamma = (const float*)d_in[9];
    float* out = (float*)d_out;

    const size_t XEL  = (size_t)B_DIM * C_DIM * N_DIM;  // 2,097,152
    const size_t QKV  = (size_t)HB * N_DIM * HD;        // 4,194,304

    short* XS  = (short*)d_ws;
    short* YS  = XS + XEL;
    short* WSx = YS + XEL;            // 512*256
    short* WSy = WSx + 512 * C_DIM;   // 1088*256
    short* QS  = WSy + 1088 * C_DIM;
    short* KS  = QS + QKV;
    short* VSu = KS + QKV;
    short* VS  = VSu + QKV;
    float* YPb = (float*)(VS + QKV);
    float* RSp = YPb + (size_t)B_DIM * N_DIM * HD;      // 2 * HB * N

    dim3 blk(256);
    cast_transpose_xy<<<dim3(N_DIM / 64, C_DIM / 64, 8), blk, 0, stream>>>(x, y, XS, YS);
    cast_weights<<<dim3(200), blk, 0, stream>>>(Wq, Wk, Wv, Wp, WSx, WSy);

    proj_all<<<dim3(NTOK / 128, 25), blk, 0, stream>>>(
        WSx, WSy, XS, YS, bq, bk, bv, QS, KS, VSu, YPb);

    rowsum_mfma<<<dim3(1024), blk, 0, stream>>>(QS, KS, RSp);
    v_scale<<<dim3(2048), blk, 0, stream>>>(VSu, RSp, VS);
    init_out<<<dim3(4096), blk, 0, stream>>>(YPb, gamma, out);
    attnout_mfma<<<dim3(1024), blk, 0, stream>>>(QS, KS, VS, gamma, out);
}

// Round 10
// 218.002 us; speedup vs baseline: 1.2567x; 1.0280x over previous
//
#include <hip/hip_runtime.h>
#include <math.h>

#define B_DIM 4
#define C_DIM 256
#define N_DIM 2048
#define H_DIM 8
#define HD    64
#define HB    32                 // H*B
#define NTOK  (B_DIM * N_DIM)    // 8192
#define LOG2E 1.44269504f

typedef __attribute__((ext_vector_type(8))) short bf16x8;
typedef __attribute__((ext_vector_type(4))) float f32x4;

static __device__ __forceinline__ short f2bf(float f) {          // RNE (cold paths)
    unsigned u = __builtin_bit_cast(unsigned, f);
    u += 0x7fffu + ((u >> 16) & 1u);
    return (short)(u >> 16);
}
static __device__ __forceinline__ float bf2f(short s) {
    unsigned u = ((unsigned)(unsigned short)s) << 16;
    return __builtin_bit_cast(float, u);
}
// pack two fp32 -> two bf16 in one dword (HW packed cvt when available)
static __device__ __forceinline__ unsigned pk_bf16(float a, float b) {
#if __has_builtin(__builtin_amdgcn_cvt_pk_bf16_f32)
    auto v = __builtin_amdgcn_cvt_pk_bf16_f32(a, b);
    return __builtin_bit_cast(unsigned, v);
#else
    unsigned ua = __builtin_bit_cast(unsigned, a);
    unsigned ub = __builtin_bit_cast(unsigned, b);
    return ((ua + 0x8000u) >> 16) | ((ub + 0x8000u) & 0xffff0000u);
#endif
}

#define MFMA16(A, Bv, Cv) __builtin_amdgcn_mfma_f32_16x16x32_bf16(A, Bv, Cv, 0, 0, 0)

// Fragment-major layouts (fragment = 64 lanes x 16 B = 1 KB contiguous):
//   QS/KS(hb, rt, ks, lane, j) = M[hb][n = rt*16 + (lane&15)][d = ks*32 + (lane>>4)*8 + j]
//   (QS holds Q * log2e so exp() becomes exp2())
//   VS(hb, nb, ks, dt, lane, j) = V[hb][d = dt*16+(lane&15)][n = nb*64+ks*32+(lane>>4)*8+j]
//   XS/YS(rt, ks, lane, j) = X[tok = rt*16+(lane&15)][c = ks*32+(lane>>4)*8+j]
//   WS(ot, ks, lane, j)    = W[o  = ot*16+(lane&15)][c = ks*32+(lane>>4)*8+j]

// ---------------------------------------------------------------------------
// cast+transpose to fragment-major: z<4 -> x batch z, z>=4 -> y batch z-4
// ---------------------------------------------------------------------------
__global__ __launch_bounds__(256) void cast_transpose_xy(
    const float* __restrict__ X, const float* __restrict__ Y,
    short* __restrict__ XS, short* __restrict__ YS)
{
    const int z = blockIdx.z;
    const float* src = (z < 4) ? X : Y;
    short* dst = (z < 4) ? XS : YS;
    const int b = z & 3, c0 = blockIdx.y * 64, n0 = blockIdx.x * 64;
    __shared__ float L[64][65];   // [c_local][n_local]
    const int t = threadIdx.x;
    for (int i = t; i < 4096; i += 256) {
        int cc = i >> 6, nn = i & 63;
        L[cc][nn] = src[((size_t)b * C_DIM + c0 + cc) * N_DIM + n0 + nn];
    }
    __syncthreads();
#pragma unroll
    for (int half = 0; half < 2; ++half) {
        int cid = half * 256 + t;
        int lane = cid & 63, fi = cid >> 6;      // fi 0..7
        int ksl = fi & 1, rtl = fi >> 1;         // rtl 0..3
        int lo = lane & 15, quad = lane >> 4;
        bf16x8 o;
#pragma unroll
        for (int j = 0; j < 8; ++j) o[j] = f2bf(L[ksl * 32 + quad * 8 + j][rtl * 16 + lo]);
        int rt = b * 128 + (n0 >> 4) + rtl;
        int ks = (c0 >> 5) + ksl;
        *(bf16x8*)(dst + ((size_t)(rt * 8 + ks) * 64 + lane) * 8) = o;
    }
}

// ---------------------------------------------------------------------------
// weights fp32 -> bf16 fragment-major: WSx = Wq (32 ot); WSy = [Wk;Wv;Wp] (68 ot)
// ---------------------------------------------------------------------------
__global__ __launch_bounds__(256) void cast_weights(
    const float* __restrict__ Wq, const float* __restrict__ Wk,
    const float* __restrict__ Wv, const float* __restrict__ Wp,
    short* __restrict__ WSx, short* __restrict__ WSy)
{
    int gid = blockIdx.x * 256 + threadIdx.x;   // 0..51199
    int lane = gid & 63, chunk = gid >> 6;      // chunk 0..799
    int lo = lane & 15, quad = lane >> 4;
    const float* src; short* dst;
    if (chunk < 256) {                           // Wq -> WSx
        int ot = chunk >> 3, ks = chunk & 7;
        src = Wq + (size_t)(ot * 16 + lo) * C_DIM + ks * 32 + quad * 8;
        dst = WSx + (size_t)chunk * 512 + lane * 8;
    } else {                                     // Wk|Wv|Wp -> WSy
        int ch = chunk - 256;
        int ot = ch >> 3, ks = ch & 7;
        int row = ot * 16 + lo;
        const float* base = (row < 512) ? (Wk + (size_t)row * C_DIM)
                          : (row < 1024) ? (Wv + (size_t)(row - 512) * C_DIM)
                                         : (Wp + (size_t)(row - 1024) * C_DIM);
        src = base + ks * 32 + quad * 8;
        dst = WSy + (size_t)ch * 512 + lane * 8;
    }
    bf16x8 o;
#pragma unroll
    for (int j = 0; j < 8; ++j) o[j] = f2bf(src[j]);
    *(bf16x8*)dst = o;
}

// ---------------------------------------------------------------------------
// Merged MFMA projection, all loads coalesced fragment loads.
// oy<8: Q=(Wq x + bq)*log2e -> QS. oy 8..15: K -> KS. oy 16..23: V -> VSu.
// oy==24: YP fp32 (b,n,d). Epilogue: LDS transpose -> coalesced 16B stores.
// ---------------------------------------------------------------------------
__global__ __launch_bounds__(256) void proj_all(
    const short* __restrict__ WSx, const short* __restrict__ WSy,
    const short* __restrict__ XS, const short* __restrict__ YS,
    const float* __restrict__ bq, const float* __restrict__ bk,
    const float* __restrict__ bv,
    short* __restrict__ QS, short* __restrict__ KS,
    short* __restrict__ VSu, float* __restrict__ Yo)
{
    const int oy = blockIdx.y;
    const bool isq = oy < 8;
    const short* WS = isq ? WSx : WSy;
    const short* Xs = isq ? XS : YS;
    const int oyl = isq ? oy : oy - 8;
    const int o0 = oyl * 64;
    const int tok0 = blockIdx.x * 128;
    const int t = threadIdx.x, wave = t >> 6, lane = t & 63;
    const int lo = lane & 15, quad = lane >> 4;

    __shared__ __align__(16) char smem[34816];

    const int ot = oyl * 4 + wave;
    const int rt0 = tok0 >> 4;

    f32x4 acc[8];
#pragma unroll
    for (int i = 0; i < 8; ++i) acc[i] = (f32x4){0.f, 0.f, 0.f, 0.f};

#pragma unroll 2
    for (int ks = 0; ks < 8; ++ks) {
        bf16x8 a = *(const bf16x8*)(WS + ((size_t)(ot * 8 + ks) * 64 + lane) * 8);
#pragma unroll
        for (int nt = 0; nt < 8; ++nt) {
            bf16x8 bx = *(const bf16x8*)(Xs + ((size_t)((rt0 + nt) * 8 + ks) * 64 + lane) * 8);
            acc[nt] = MFMA16(a, bx, acc[nt]);
        }
    }

    const int b = tok0 >> 11;
    const int n0b = tok0 & (N_DIM - 1);

    if (oy < 16) {
        // ---- Q or K: T[128][72] bf16 -> fragment-major QS/KS ----
        short* T = (short*)smem;
        const float* bias = isq ? bq : bk;
        const float scale = isq ? LOG2E : 1.f;
        float bvr[4];
#pragma unroll
        for (int r = 0; r < 4; ++r) bvr[r] = bias[o0 + wave * 16 + quad * 4 + r];
#pragma unroll
        for (int nt = 0; nt < 8; ++nt) {
            short4 pk;
            pk.x = f2bf((acc[nt][0] + bvr[0]) * scale);
            pk.y = f2bf((acc[nt][1] + bvr[1]) * scale);
            pk.z = f2bf((acc[nt][2] + bvr[2]) * scale);
            pk.w = f2bf((acc[nt][3] + bvr[3]) * scale);
            *(short4*)(T + (nt * 16 + lo) * 72 + wave * 16 + quad * 4) = pk;
        }
        __syncthreads();
        const int h = oyl;
        const int hb = h * 4 + b;
        short* dst = isq ? QS : KS;
#pragma unroll
        for (int s = 0; s < 4; ++s) {
            int cid = s * 256 + t;
            int ln = cid & 63, fi = cid >> 6;     // fi 0..15
            int ksd = fi & 1, rtl = fi >> 1;      // rtl 0..7
            bf16x8 v = *(const bf16x8*)(T + (rtl * 16 + (ln & 15)) * 72 + ksd * 32 + (ln >> 4) * 8);
            *(bf16x8*)(dst + (((size_t)(hb * 128 + (n0b >> 4) + rtl) * 2 + ksd) * 512 + ln * 8)) = v;
        }
    } else if (oy < 24) {
        // ---- V: T2[64][136] bf16 -> fragment-major VSu ----
        short* T2 = (short*)smem;
        float bvr[4];
#pragma unroll
        for (int r = 0; r < 4; ++r) bvr[r] = bv[o0 - 512 + wave * 16 + quad * 4 + r];
#pragma unroll
        for (int nt = 0; nt < 8; ++nt)
#pragma unroll
            for (int r = 0; r < 4; ++r) {
                int ol = wave * 16 + quad * 4 + r;
                T2[ol * 136 + nt * 16 + lo] = f2bf(acc[nt][r] + bvr[r]);
            }
        __syncthreads();
        const int h = oy - 16;
        const int hb = h * 4 + b;
#pragma unroll
        for (int s = 0; s < 4; ++s) {
            int cid = s * 256 + t;
            int ln = cid & 63, fi = cid >> 6;     // fi 0..15
            int dt = fi & 3, ksd = (fi >> 2) & 1, nbl = fi >> 3;
            int dl = dt * 16 + (ln & 15);
            int tkl = nbl * 64 + ksd * 32 + (ln >> 4) * 8;
            bf16x8 v = *(const bf16x8*)(T2 + dl * 136 + tkl);
            int nbg = (n0b >> 6) + nbl;
            *(bf16x8*)(VSu + ((size_t)(((hb * 32 + nbg) * 2 + ksd) * 4 + dt) * 64 + ln) * 8) = v;
        }
    } else {
        // ---- YP: T3[128][68] fp32 -> (b,n,d) float4 stores ----
        float* T3 = (float*)smem;
#pragma unroll
        for (int nt = 0; nt < 8; ++nt) {
            float4 f;
            f.x = acc[nt][0]; f.y = acc[nt][1]; f.z = acc[nt][2]; f.w = acc[nt][3];
            *(float4*)(T3 + (nt * 16 + lo) * 68 + wave * 16 + quad * 4) = f;
        }
        __syncthreads();
#pragma unroll
        for (int s = 0; s < 8; ++s) {
            int cid = s * 256 + t;
            int row = cid >> 4, c4 = (cid & 15) * 4;
            float4 f = *(const float4*)(T3 + row * 68 + c4);
            *(float4*)(Yo + ((size_t)(tok0 + row)) * 64 + c4) = f;
        }
    }
}

// ---------------------------------------------------------------------------
// rowsum partials: RSp[z][hb][n] = sum over m-half z of exp2(Q'[n].K[m]).
// ---------------------------------------------------------------------------
__global__ __launch_bounds__(256, 4) void rowsum_mfma(
    const short* __restrict__ QS, const short* __restrict__ KS,
    float* __restrict__ RSp)
{
    const int id = blockIdx.x;
    const int hb = ((id & 7) << 2) | ((id >> 3) & 3);
    const int z = (id >> 5) & 1;
    const int n0 = (id >> 6) * 128;
    const int mbeg = z * (N_DIM / 2);
    const int t = threadIdx.x, wave = t >> 6, lane = t & 63;
    const int lo = lane & 15, quad = lane >> 4;

    bf16x8 a0[2], a1[2];
#pragma unroll
    for (int s = 0; s < 2; ++s) {
        int rt = (n0 >> 4) + s * 4 + wave;
        a0[s] = *(const bf16x8*)(QS + ((size_t)(hb * 128 + rt) * 2 + 0) * 512 + lane * 8);
        a1[s] = *(const bf16x8*)(QS + ((size_t)(hb * 128 + rt) * 2 + 1) * 512 + lane * 8);
    }

    float sm[2][4];
#pragma unroll
    for (int s = 0; s < 2; ++s)
#pragma unroll
        for (int r = 0; r < 4; ++r) sm[s][r] = 0.f;

    for (int m0 = mbeg; m0 < mbeg + N_DIM / 2; m0 += 64) {
#pragma unroll
        for (int mt = 0; mt < 4; ++mt) {
            int rtk = (m0 >> 4) + mt;
            bf16x8 b0 = *(const bf16x8*)(KS + ((size_t)(hb * 128 + rtk) * 2 + 0) * 512 + lane * 8);
            bf16x8 b1 = *(const bf16x8*)(KS + ((size_t)(hb * 128 + rtk) * 2 + 1) * 512 + lane * 8);
#pragma unroll
            for (int s = 0; s < 2; ++s) {
                f32x4 c = {0.f, 0.f, 0.f, 0.f};
                c = MFMA16(a0[s], b0, c);
                c = MFMA16(a1[s], b1, c);
#pragma unroll
                for (int r = 0; r < 4; ++r) sm[s][r] += exp2f(c[r]);
            }
        }
    }

#pragma unroll
    for (int sft = 1; sft < 16; sft <<= 1)
#pragma unroll
        for (int s = 0; s < 2; ++s)
#pragma unroll
            for (int r = 0; r < 4; ++r) sm[s][r] += __shfl_xor(sm[s][r], sft);

    if (lo == 0) {
#pragma unroll
        for (int s = 0; s < 2; ++s) {
            int row = n0 + s * 64 + wave * 16 + quad * 4;
#pragma unroll
            for (int r = 0; r < 4; ++r)
                RSp[((size_t)z * HB + hb) * N_DIM + row + r] = sm[s][r];
        }
    }
}

// ---------------------------------------------------------------------------
// VS = VSu * 1/(RSp0[n]+RSp1[n]) — same fragment-major layout in and out
// ---------------------------------------------------------------------------
__global__ __launch_bounds__(256) void v_scale(
    const short* __restrict__ VSu, const float* __restrict__ RSp,
    short* __restrict__ VS)
{
    int t = blockIdx.x * 256 + threadIdx.x;     // 0..524287
    int lane = t & 63, fidx = t >> 6;
    int ks = (fidx >> 2) & 1, nb = (fidx >> 3) & 31, hb = fidx >> 8;
    int n = nb * 64 + ks * 32 + (lane >> 4) * 8;
    bf16x8 v = *(const bf16x8*)(VSu + (size_t)t * 8);
    const float* r0 = RSp + (size_t)hb * N_DIM + n;
    const float* r1 = r0 + (size_t)HB * N_DIM;
    bf16x8 o;
#pragma unroll
    for (int j = 0; j < 8; ++j) o[j] = f2bf(bf2f(v[j]) / (r0[j] + r1[j]));
    *(bf16x8*)(VS + (size_t)t * 8) = o;
}

// ---------------------------------------------------------------------------
// attnout: PA_z[hb,m,d] (bf16, out-layout) = sum_{n in half z} exp2(Q'.K) Vsc
// 128-m tile x n-half. 1024 blocks. Coalesced fragment loads; P via
// XOR-swizzled per-wave LDS; no barriers in main loop; epilogue LDS
// transpose -> fully coalesced 16B bf16 partial stores (no atomics).
// ---------------------------------------------------------------------------
__global__ __launch_bounds__(256, 4) void attnout_mfma(
    const short* __restrict__ QS, const short* __restrict__ KS,
    const short* __restrict__ VS,
    short* __restrict__ PA0, short* __restrict__ PA1)
{
    const int id = blockIdx.x;
    const int hb = ((id & 7) << 2) | ((id >> 3) & 3);
    const int z = (id >> 5) & 1;
    const int m0 = (id >> 6) * 128;
    const int nbeg = z * (N_DIM / 2);

    __shared__ __align__(16) char smem[17408];   // Pl (16 KB) / epilogue T (17.4 KB)
    short* Pl = (short*)smem;

    const int t = threadIdx.x, wave = t >> 6, lane = t & 63;
    const int lo = lane & 15, quad = lane >> 4;

    bf16x8 bk0[2], bk1[2];
#pragma unroll
    for (int s = 0; s < 2; ++s) {
        int rt = (m0 >> 4) + s * 4 + wave;
        bk0[s] = *(const bf16x8*)(KS + ((size_t)(hb * 128 + rt) * 2 + 0) * 512 + lane * 8);
        bk1[s] = *(const bf16x8*)(KS + ((size_t)(hb * 128 + rt) * 2 + 1) * 512 + lane * 8);
    }

    f32x4 oacc[2][4];
#pragma unroll
    for (int s = 0; s < 2; ++s)
#pragma unroll
        for (int dt = 0; dt < 4; ++dt) oacc[s][dt] = (f32x4){0.f, 0.f, 0.f, 0.f};

    for (int n0 = nbeg; n0 < nbeg + N_DIM / 2; n0 += 64) {
        // ---- QK -> P = exp2(E'), unnormalized (1/rowsum folded into VS) ----
#pragma unroll
        for (int nt = 0; nt < 4; ++nt) {
            int rt = (n0 >> 4) + nt;
            bf16x8 a0 = *(const bf16x8*)(QS + ((size_t)(hb * 128 + rt) * 2 + 0) * 512 + lane * 8);
            bf16x8 a1 = *(const bf16x8*)(QS + ((size_t)(hb * 128 + rt) * 2 + 1) * 512 + lane * 8);
#pragma unroll
            for (int s = 0; s < 2; ++s) {
                f32x4 c = {0.f, 0.f, 0.f, 0.f};
                c = MFMA16(a0, bk0[s], c);
                c = MFMA16(a1, bk1[s], c);
                uint2 pk;
                pk.x = pk_bf16(exp2f(c[0]), exp2f(c[1]));
                pk.y = pk_bf16(exp2f(c[2]), exp2f(c[3]));
                int row = s * 64 + wave * 16 + lo;          // row&7 == lo&7
                int chunk = nt * 2 + (quad >> 1);
                *(uint2*)(Pl + row * 64 + (((chunk ^ (lo & 7)) << 3) | ((quad & 1) << 2))) = pk;
            }
        }
        // ---- PV ----
        int nb = n0 >> 6;
#pragma unroll
        for (int ks = 0; ks < 2; ++ks) {
            bf16x8 ap[2];
#pragma unroll
            for (int s = 0; s < 2; ++s) {
                int row = s * 64 + wave * 16 + lo;
                ap[s] = *(const bf16x8*)(Pl + row * 64 + (((ks * 4 + quad) ^ (lo & 7)) << 3));
            }
#pragma unroll
            for (int dt = 0; dt < 4; ++dt) {
                bf16x8 bv = *(const bf16x8*)(
                    VS + ((size_t)(((hb * 32 + nb) * 2 + ks) * 4 + dt) * 64 + lane) * 8);
                oacc[0][dt] = MFMA16(ap[0], bv, oacc[0][dt]);
                oacc[1][dt] = MFMA16(ap[1], bv, oacc[1][dt]);
            }
        }
    }

    // ---- epilogue: LDS transpose -> coalesced bf16 partial stores ----
    short* PA = z ? PA1 : PA0;
    float* T = (float*)smem;                      // [64][68]
#pragma unroll
    for (int s = 0; s < 2; ++s) {
        __syncthreads();                          // Pl / previous T reads done
#pragma unroll
        for (int dt = 0; dt < 4; ++dt)
#pragma unroll
            for (int r = 0; r < 4; ++r)
                T[(wave * 16 + quad * 4 + r) * 68 + dt * 16 + lo] = oacc[s][dt][r];
        __syncthreads();
#pragma unroll
        for (int it = 0; it < 2; ++it) {
            int idx = it * 256 + t;               // 0..511
            int rowl = idx >> 3, dg = (idx & 7) * 8;
            float4 f0 = *(const float4*)(T + rowl * 68 + dg);
            float4 f1 = *(const float4*)(T + rowl * 68 + dg + 4);
            uint4 o;
            o.x = pk_bf16(f0.x, f0.y);
            o.y = pk_bf16(f0.z, f0.w);
            o.z = pk_bf16(f1.x, f1.y);
            o.w = pk_bf16(f1.z, f1.w);
            int m = m0 + s * 64 + rowl;
            *(uint4*)(PA + ((size_t)(hb * N_DIM + m)) * 64 + dg) = o;
        }
    }
}

// ---------------------------------------------------------------------------
// out = g/(1+g) * (PA0 + PA1) + YP/(1+g)
// ---------------------------------------------------------------------------
__global__ __launch_bounds__(256) void combine_out(
    const short* __restrict__ PA0, const short* __restrict__ PA1,
    const float* __restrict__ YP, const float* __restrict__ gamma,
    float* __restrict__ out)
{
    size_t flat = ((size_t)blockIdx.x * 256 + threadIdx.x) * 8;
    int d  = (int)(flat & 63);
    int n  = (int)((flat >> 6) & (N_DIM - 1));
    int hb = (int)(flat >> 17);
    int h = hb >> 2, b = hb & 3;
    float g = gamma[h];
    float inv = 1.f / (1.f + g);
    float gi = g * inv;
    bf16x8 p0 = *(const bf16x8*)(PA0 + flat);
    bf16x8 p1 = *(const bf16x8*)(PA1 + flat);
    const float* yp = YP + ((size_t)b * N_DIM + n) * HD + d;
    float o[8];
#pragma unroll
    for (int j = 0; j < 8; ++j)
        o[j] = gi * (bf2f(p0[j]) + bf2f(p1[j])) + inv * yp[j];
    float4 o0 = {o[0], o[1], o[2], o[3]};
    float4 o1 = {o[4], o[5], o[6], o[7]};
    *(float4*)(out + flat) = o0;
    *(float4*)(out + flat + 4) = o1;
}

// ---------------------------------------------------------------------------
extern "C" void kernel_launch(void* const* d_in, const int* in_sizes, int n_in,
                              void* d_out, int out_size, void* d_ws, size_t ws_size,
                              hipStream_t stream) {
    const float* x     = (const float*)d_in[0];
    const float* y     = (const float*)d_in[1];
    const float* Wq    = (const float*)d_in[2];
    const float* bq    = (const float*)d_in[3];
    const float* Wk    = (const float*)d_in[4];
    const float* bk    = (const float*)d_in[5];
    const float* Wv    = (const float*)d_in[6];
    const float* bv    = (const float*)d_in[7];
    const float* Wp    = (const float*)d_in[8];
    const float* gamma = (const float*)d_in[9];
    float* out = (float*)d_out;

    const size_t XEL  = (size_t)B_DIM * C_DIM * N_DIM;  // 2,097,152
    const size_t QKV  = (size_t)HB * N_DIM * HD;        // 4,194,304

    short* XS  = (short*)d_ws;
    short* YS  = XS + XEL;
    short* WSx = YS + XEL;            // 512*256
    short* WSy = WSx + 512 * C_DIM;   // 1088*256
    short* QS  = WSy + 1088 * C_DIM;
    short* KS  = QS + QKV;
    short* VSu = KS + QKV;
    short* VS  = VSu + QKV;
    float* YPb = (float*)(VS + QKV);
    float* RSp = YPb + (size_t)B_DIM * N_DIM * HD;      // 2 * HB * N
    // overlays (dead after their producers/consumers finish):
    short* PA0 = XS;                  // XS+YS region = exactly QKV shorts
    short* PA1 = VSu;                 // VSu dead after v_scale

    dim3 blk(256);
    cast_transpose_xy<<<dim3(N_DIM / 64, C_DIM / 64, 8), blk, 0, stream>>>(x, y, XS, YS);
    cast_weights<<<dim3(200), blk, 0, stream>>>(Wq, Wk, Wv, Wp, WSx, WSy);

    proj_all<<<dim3(NTOK / 128, 25), blk, 0, stream>>>(
        WSx, WSy, XS, YS, bq, bk, bv, QS, KS, VSu, YPb);

    rowsum_mfma<<<dim3(1024), blk, 0, stream>>>(QS, KS, RSp);
    v_scale<<<dim3(2048), blk, 0, stream>>>(VSu, RSp, VS);
    attnout_mfma<<<dim3(1024), blk, 0, stream>>>(QS, KS, VS, PA0, PA1);
    combine_out<<<dim3(2048), blk, 0, stream>>>(PA0, PA1, YPb, gamma, out);
}

// Round 11
// 192.682 us; speedup vs baseline: 1.4218x; 1.1314x over previous
//
#include <hip/hip_runtime.h>
#include <math.h>

#define B_DIM 4
#define C_DIM 256
#define N_DIM 2048
#define H_DIM 8
#define HD    64
#define HB    32                 // H*B
#define NTOK  (B_DIM * N_DIM)    // 8192
#define LOG2E 1.44269504f

typedef __attribute__((ext_vector_type(8))) short bf16x8;
typedef __attribute__((ext_vector_type(4))) float f32x4;

static __device__ __forceinline__ short f2bf(float f) {          // RNE (cold paths)
    unsigned u = __builtin_bit_cast(unsigned, f);
    u += 0x7fffu + ((u >> 16) & 1u);
    return (short)(u >> 16);
}
static __device__ __forceinline__ float bf2f(short s) {
    unsigned u = ((unsigned)(unsigned short)s) << 16;
    return __builtin_bit_cast(float, u);
}
// raw v_exp_f32: exact for |x| <~ 126, skips OCML's range-guard sequence
static __device__ __forceinline__ float fx2(float x) {
#if __has_builtin(__builtin_amdgcn_exp2f)
    return __builtin_amdgcn_exp2f(x);
#else
    return exp2f(x);
#endif
}
// pack two fp32 -> two bf16 in one dword (HW packed cvt when available)
static __device__ __forceinline__ unsigned pk_bf16(float a, float b) {
#if __has_builtin(__builtin_amdgcn_cvt_pk_bf16_f32)
    auto v = __builtin_amdgcn_cvt_pk_bf16_f32(a, b);
    return __builtin_bit_cast(unsigned, v);
#else
    unsigned ua = __builtin_bit_cast(unsigned, a);
    unsigned ub = __builtin_bit_cast(unsigned, b);
    return ((ua + 0x8000u) >> 16) | ((ub + 0x8000u) & 0xffff0000u);
#endif
}

#define MFMA16(A, Bv, Cv) __builtin_amdgcn_mfma_f32_16x16x32_bf16(A, Bv, Cv, 0, 0, 0)

// Fragment-major layouts (fragment = 64 lanes x 16 B = 1 KB contiguous):
//   QS/KS(hb, rt, ks, lane, j) = M[hb][n = rt*16 + (lane&15)][d = ks*32 + (lane>>4)*8 + j]
//   (QS holds Q * log2e so exp() becomes exp2())
//   VS(hb, nb, ks, dt, lane, j) = V[hb][d = dt*16+(lane&15)][n = nb*64+ks*32+(lane>>4)*8+j]
//   XS/YS(rt, ks, lane, j) = X[tok = rt*16+(lane&15)][c = ks*32+(lane>>4)*8+j]
//   WS(ot, ks, lane, j)    = W[o  = ot*16+(lane&15)][c = ks*32+(lane>>4)*8+j]

// ---------------------------------------------------------------------------
// cast+transpose to fragment-major: z<4 -> x batch z, z>=4 -> y batch z-4
// ---------------------------------------------------------------------------
__global__ __launch_bounds__(256) void cast_transpose_xy(
    const float* __restrict__ X, const float* __restrict__ Y,
    short* __restrict__ XS, short* __restrict__ YS)
{
    const int z = blockIdx.z;
    const float* src = (z < 4) ? X : Y;
    short* dst = (z < 4) ? XS : YS;
    const int b = z & 3, c0 = blockIdx.y * 64, n0 = blockIdx.x * 64;
    __shared__ float L[64][65];   // [c_local][n_local]
    const int t = threadIdx.x;
    for (int i = t; i < 4096; i += 256) {
        int cc = i >> 6, nn = i & 63;
        L[cc][nn] = src[((size_t)b * C_DIM + c0 + cc) * N_DIM + n0 + nn];
    }
    __syncthreads();
#pragma unroll
    for (int half = 0; half < 2; ++half) {
        int cid = half * 256 + t;
        int lane = cid & 63, fi = cid >> 6;      // fi 0..7
        int ksl = fi & 1, rtl = fi >> 1;         // rtl 0..3
        int lo = lane & 15, quad = lane >> 4;
        bf16x8 o;
#pragma unroll
        for (int j = 0; j < 8; ++j) o[j] = f2bf(L[ksl * 32 + quad * 8 + j][rtl * 16 + lo]);
        int rt = b * 128 + (n0 >> 4) + rtl;
        int ks = (c0 >> 5) + ksl;
        *(bf16x8*)(dst + ((size_t)(rt * 8 + ks) * 64 + lane) * 8) = o;
    }
}

// ---------------------------------------------------------------------------
// weights fp32 -> bf16 fragment-major: WSx = Wq (32 ot); WSy = [Wk;Wv;Wp] (68 ot)
// ---------------------------------------------------------------------------
__global__ __launch_bounds__(256) void cast_weights(
    const float* __restrict__ Wq, const float* __restrict__ Wk,
    const float* __restrict__ Wv, const float* __restrict__ Wp,
    short* __restrict__ WSx, short* __restrict__ WSy)
{
    int gid = blockIdx.x * 256 + threadIdx.x;   // 0..51199
    int lane = gid & 63, chunk = gid >> 6;      // chunk 0..799
    int lo = lane & 15, quad = lane >> 4;
    const float* src; short* dst;
    if (chunk < 256) {                           // Wq -> WSx
        int ot = chunk >> 3, ks = chunk & 7;
        src = Wq + (size_t)(ot * 16 + lo) * C_DIM + ks * 32 + quad * 8;
        dst = WSx + (size_t)chunk * 512 + lane * 8;
    } else {                                     // Wk|Wv|Wp -> WSy
        int ch = chunk - 256;
        int ot = ch >> 3, ks = ch & 7;
        int row = ot * 16 + lo;
        const float* base = (row < 512) ? (Wk + (size_t)row * C_DIM)
                          : (row < 1024) ? (Wv + (size_t)(row - 512) * C_DIM)
                                         : (Wp + (size_t)(row - 1024) * C_DIM);
        src = base + ks * 32 + quad * 8;
        dst = WSy + (size_t)ch * 512 + lane * 8;
    }
    bf16x8 o;
#pragma unroll
    for (int j = 0; j < 8; ++j) o[j] = f2bf(src[j]);
    *(bf16x8*)dst = o;
}

// ---------------------------------------------------------------------------
// Merged MFMA projection, all loads coalesced fragment loads.
// oy<8: Q=(Wq x + bq)*log2e -> QS. oy 8..15: K -> KS. oy 16..23: V -> VSu.
// oy==24: YP fp32 (b,n,d). Epilogue: LDS transpose -> coalesced 16B stores.
// ---------------------------------------------------------------------------
__global__ __launch_bounds__(256) void proj_all(
    const short* __restrict__ WSx, const short* __restrict__ WSy,
    const short* __restrict__ XS, const short* __restrict__ YS,
    const float* __restrict__ bq, const float* __restrict__ bk,
    const float* __restrict__ bv,
    short* __restrict__ QS, short* __restrict__ KS,
    short* __restrict__ VSu, float* __restrict__ Yo)
{
    const int oy = blockIdx.y;
    const bool isq = oy < 8;
    const short* WS = isq ? WSx : WSy;
    const short* Xs = isq ? XS : YS;
    const int oyl = isq ? oy : oy - 8;
    const int o0 = oyl * 64;
    const int tok0 = blockIdx.x * 128;
    const int t = threadIdx.x, wave = t >> 6, lane = t & 63;
    const int lo = lane & 15, quad = lane >> 4;

    __shared__ __align__(16) char smem[34816];

    const int ot = oyl * 4 + wave;
    const int rt0 = tok0 >> 4;
    const f32x4 czero = {0.f, 0.f, 0.f, 0.f};

    f32x4 acc[8];
#pragma unroll
    for (int i = 0; i < 8; ++i) acc[i] = czero;

#pragma unroll 2
    for (int ks = 0; ks < 8; ++ks) {
        bf16x8 a = *(const bf16x8*)(WS + ((size_t)(ot * 8 + ks) * 64 + lane) * 8);
#pragma unroll
        for (int nt = 0; nt < 8; ++nt) {
            bf16x8 bx = *(const bf16x8*)(Xs + ((size_t)((rt0 + nt) * 8 + ks) * 64 + lane) * 8);
            acc[nt] = MFMA16(a, bx, acc[nt]);
        }
    }

    const int b = tok0 >> 11;
    const int n0b = tok0 & (N_DIM - 1);

    if (oy < 16) {
        // ---- Q or K: T[128][72] bf16 -> fragment-major QS/KS ----
        short* T = (short*)smem;
        const float* bias = isq ? bq : bk;
        const float scale = isq ? LOG2E : 1.f;
        float bvr[4];
#pragma unroll
        for (int r = 0; r < 4; ++r) bvr[r] = bias[o0 + wave * 16 + quad * 4 + r];
#pragma unroll
        for (int nt = 0; nt < 8; ++nt) {
            short4 pk;
            pk.x = f2bf((acc[nt][0] + bvr[0]) * scale);
            pk.y = f2bf((acc[nt][1] + bvr[1]) * scale);
            pk.z = f2bf((acc[nt][2] + bvr[2]) * scale);
            pk.w = f2bf((acc[nt][3] + bvr[3]) * scale);
            *(short4*)(T + (nt * 16 + lo) * 72 + wave * 16 + quad * 4) = pk;
        }
        __syncthreads();
        const int h = oyl;
        const int hb = h * 4 + b;
        short* dst = isq ? QS : KS;
#pragma unroll
        for (int s = 0; s < 4; ++s) {
            int cid = s * 256 + t;
            int ln = cid & 63, fi = cid >> 6;     // fi 0..15
            int ksd = fi & 1, rtl = fi >> 1;      // rtl 0..7
            bf16x8 v = *(const bf16x8*)(T + (rtl * 16 + (ln & 15)) * 72 + ksd * 32 + (ln >> 4) * 8);
            *(bf16x8*)(dst + (((size_t)(hb * 128 + (n0b >> 4) + rtl) * 2 + ksd) * 512 + ln * 8)) = v;
        }
    } else if (oy < 24) {
        // ---- V: T2[64][136] bf16 -> fragment-major VSu ----
        short* T2 = (short*)smem;
        float bvr[4];
#pragma unroll
        for (int r = 0; r < 4; ++r) bvr[r] = bv[o0 - 512 + wave * 16 + quad * 4 + r];
#pragma unroll
        for (int nt = 0; nt < 8; ++nt)
#pragma unroll
            for (int r = 0; r < 4; ++r) {
                int ol = wave * 16 + quad * 4 + r;
                T2[ol * 136 + nt * 16 + lo] = f2bf(acc[nt][r] + bvr[r]);
            }
        __syncthreads();
        const int h = oy - 16;
        const int hb = h * 4 + b;
#pragma unroll
        for (int s = 0; s < 4; ++s) {
            int cid = s * 256 + t;
            int ln = cid & 63, fi = cid >> 6;     // fi 0..15
            int dt = fi & 3, ksd = (fi >> 2) & 1, nbl = fi >> 3;
            int dl = dt * 16 + (ln & 15);
            int tkl = nbl * 64 + ksd * 32 + (ln >> 4) * 8;
            bf16x8 v = *(const bf16x8*)(T2 + dl * 136 + tkl);
            int nbg = (n0b >> 6) + nbl;
            *(bf16x8*)(VSu + ((size_t)(((hb * 32 + nbg) * 2 + ksd) * 4 + dt) * 64 + ln) * 8) = v;
        }
    } else {
        // ---- YP: T3[128][68] fp32 -> (b,n,d) float4 stores ----
        float* T3 = (float*)smem;
#pragma unroll
        for (int nt = 0; nt < 8; ++nt) {
            float4 f;
            f.x = acc[nt][0]; f.y = acc[nt][1]; f.z = acc[nt][2]; f.w = acc[nt][3];
            *(float4*)(T3 + (nt * 16 + lo) * 68 + wave * 16 + quad * 4) = f;
        }
        __syncthreads();
#pragma unroll
        for (int s = 0; s < 8; ++s) {
            int cid = s * 256 + t;
            int row = cid >> 4, c4 = (cid & 15) * 4;
            float4 f = *(const float4*)(T3 + row * 68 + c4);
            *(float4*)(Yo + ((size_t)(tok0 + row)) * 64 + c4) = f;
        }
    }
}

// ---------------------------------------------------------------------------
// rowsum partials: RSp[z][hb][n] = sum over m-half z of exp2(Q'[n].K[m]).
// ---------------------------------------------------------------------------
__global__ __launch_bounds__(256, 4) void rowsum_mfma(
    const short* __restrict__ QS, const short* __restrict__ KS,
    float* __restrict__ RSp)
{
    const int id = blockIdx.x;
    const int hb = ((id & 7) << 2) | ((id >> 3) & 3);
    const int z = (id >> 5) & 1;
    const int n0 = (id >> 6) * 128;
    const int t = threadIdx.x, wave = t >> 6, lane = t & 63;
    const int lo = lane & 15, quad = lane >> 4;
    const f32x4 czero = {0.f, 0.f, 0.f, 0.f};

    bf16x8 a0[2], a1[2];
#pragma unroll
    for (int s = 0; s < 2; ++s) {
        int rt = (n0 >> 4) + s * 4 + wave;
        a0[s] = *(const bf16x8*)(QS + ((size_t)(hb * 128 + rt) * 2 + 0) * 512 + lane * 8);
        a1[s] = *(const bf16x8*)(QS + ((size_t)(hb * 128 + rt) * 2 + 1) * 512 + lane * 8);
    }

    float sm[2][4];
#pragma unroll
    for (int s = 0; s < 2; ++s)
#pragma unroll
        for (int r = 0; r < 4; ++r) sm[s][r] = 0.f;

    const short* kp = KS + ((size_t)(hb * 128) * 2) * 512 + lane * 8
                    + (size_t)z * (N_DIM / 2 / 16) * 2 * 512;
    for (int m0 = 0; m0 < N_DIM / 2; m0 += 64) {
#pragma unroll
        for (int mt = 0; mt < 4; ++mt) {
            bf16x8 b0 = *(const bf16x8*)(kp + (mt * 2 + 0) * 512);
            bf16x8 b1 = *(const bf16x8*)(kp + (mt * 2 + 1) * 512);
#pragma unroll
            for (int s = 0; s < 2; ++s) {
                f32x4 c = MFMA16(a0[s], b0, czero);
                c = MFMA16(a1[s], b1, c);
#pragma unroll
                for (int r = 0; r < 4; ++r) sm[s][r] += fx2(c[r]);
            }
        }
        kp += 8 * 512;
    }

#pragma unroll
    for (int sft = 1; sft < 16; sft <<= 1)
#pragma unroll
        for (int s = 0; s < 2; ++s)
#pragma unroll
            for (int r = 0; r < 4; ++r) sm[s][r] += __shfl_xor(sm[s][r], sft);

    if (lo == 0) {
#pragma unroll
        for (int s = 0; s < 2; ++s) {
            int row = n0 + s * 64 + wave * 16 + quad * 4;
#pragma unroll
            for (int r = 0; r < 4; ++r)
                RSp[((size_t)z * HB + hb) * N_DIM + row + r] = sm[s][r];
        }
    }
}

// ---------------------------------------------------------------------------
// VS = VSu * 1/(RSp0[n]+RSp1[n]) — same fragment-major layout in and out
// ---------------------------------------------------------------------------
__global__ __launch_bounds__(256) void v_scale(
    const short* __restrict__ VSu, const float* __restrict__ RSp,
    short* __restrict__ VS)
{
    int t = blockIdx.x * 256 + threadIdx.x;     // 0..524287
    int lane = t & 63, fidx = t >> 6;
    int ks = (fidx >> 2) & 1, nb = (fidx >> 3) & 31, hb = fidx >> 8;
    int n = nb * 64 + ks * 32 + (lane >> 4) * 8;
    bf16x8 v = *(const bf16x8*)(VSu + (size_t)t * 8);
    const float* r0 = RSp + (size_t)hb * N_DIM + n;
    const float* r1 = r0 + (size_t)HB * N_DIM;
    bf16x8 o;
#pragma unroll
    for (int j = 0; j < 8; ++j) o[j] = f2bf(bf2f(v[j]) / (r0[j] + r1[j]));
    *(bf16x8*)(VS + (size_t)t * 8) = o;
}

// ---------------------------------------------------------------------------
// attnout: PA_z[hb,m,d] (bf16, out-layout) = sum_{n in half z} exp2(Q'.K) Vsc
// 128-m tile x n-half. 1024 blocks. Coalesced fragment loads; P via
// XOR-swizzled per-wave LDS; no barriers in main loop; epilogue LDS
// transpose -> fully coalesced 16B bf16 partial stores (no atomics).
// ---------------------------------------------------------------------------
__global__ __launch_bounds__(256, 4) void attnout_mfma(
    const short* __restrict__ QS, const short* __restrict__ KS,
    const short* __restrict__ VS,
    short* __restrict__ PA0, short* __restrict__ PA1)
{
    const int id = blockIdx.x;
    const int hb = ((id & 7) << 2) | ((id >> 3) & 3);
    const int z = (id >> 5) & 1;
    const int m0 = (id >> 6) * 128;

    __shared__ __align__(16) char smem[17408];   // Pl (16 KB) / epilogue T (17.4 KB)
    short* Pl = (short*)smem;

    const int t = threadIdx.x, wave = t >> 6, lane = t & 63;
    const int lo = lane & 15, quad = lane >> 4;
    const f32x4 czero = {0.f, 0.f, 0.f, 0.f};

    bf16x8 bk0[2], bk1[2];
#pragma unroll
    for (int s = 0; s < 2; ++s) {
        int rt = (m0 >> 4) + s * 4 + wave;
        bk0[s] = *(const bf16x8*)(KS + ((size_t)(hb * 128 + rt) * 2 + 0) * 512 + lane * 8);
        bk1[s] = *(const bf16x8*)(KS + ((size_t)(hb * 128 + rt) * 2 + 1) * 512 + lane * 8);
    }

    f32x4 oacc[2][4];
#pragma unroll
    for (int s = 0; s < 2; ++s)
#pragma unroll
        for (int dt = 0; dt < 4; ++dt) oacc[s][dt] = czero;

    // per-iter advanced base pointers (constant strides -> foldable offsets)
    const short* qp = QS + ((size_t)(hb * 128) * 2) * 512 + lane * 8
                    + (size_t)z * (N_DIM / 2 / 16) * 2 * 512;
    const short* vp = VS + ((size_t)(hb * 32) * 8) * 512 + lane * 8
                    + (size_t)z * (N_DIM / 2 / 64) * 8 * 512;
    short* prowA = Pl + (wave * 16 + lo) * 64;
    short* prowB = prowA + 64 * 64;
    const int lh = lo & 7;

    for (int n0 = 0; n0 < N_DIM / 2; n0 += 64) {
        // ---- QK -> P = exp2(E'), unnormalized (1/rowsum folded into VS) ----
#pragma unroll
        for (int nt = 0; nt < 4; ++nt) {
            bf16x8 a0 = *(const bf16x8*)(qp + (nt * 2 + 0) * 512);
            bf16x8 a1 = *(const bf16x8*)(qp + (nt * 2 + 1) * 512);
#pragma unroll
            for (int s = 0; s < 2; ++s) {
                f32x4 c = MFMA16(a0, bk0[s], czero);
                c = MFMA16(a1, bk1[s], c);
                uint2 pk;
                pk.x = pk_bf16(fx2(c[0]), fx2(c[1]));
                pk.y = pk_bf16(fx2(c[2]), fx2(c[3]));
                int chunk = nt * 2 + (quad >> 1);
                *(uint2*)((s ? prowB : prowA) + (((chunk ^ lh) << 3) | ((quad & 1) << 2))) = pk;
            }
        }
        // ---- PV ----
#pragma unroll
        for (int ks = 0; ks < 2; ++ks) {
            bf16x8 ap0 = *(const bf16x8*)(prowA + (((ks * 4 + quad) ^ lh) << 3));
            bf16x8 ap1 = *(const bf16x8*)(prowB + (((ks * 4 + quad) ^ lh) << 3));
#pragma unroll
            for (int dt = 0; dt < 4; ++dt) {
                bf16x8 bv = *(const bf16x8*)(vp + (ks * 4 + dt) * 512);
                oacc[0][dt] = MFMA16(ap0, bv, oacc[0][dt]);
                oacc[1][dt] = MFMA16(ap1, bv, oacc[1][dt]);
            }
        }
        qp += 8 * 512;
        vp += 8 * 512;
    }

    // ---- epilogue: LDS transpose -> coalesced bf16 partial stores ----
    short* PA = z ? PA1 : PA0;
    float* T = (float*)smem;                      // [64][68]
#pragma unroll
    for (int s = 0; s < 2; ++s) {
        __syncthreads();                          // Pl / previous T reads done
#pragma unroll
        for (int dt = 0; dt < 4; ++dt)
#pragma unroll
            for (int r = 0; r < 4; ++r)
                T[(wave * 16 + quad * 4 + r) * 68 + dt * 16 + lo] = oacc[s][dt][r];
        __syncthreads();
#pragma unroll
        for (int it = 0; it < 2; ++it) {
            int idx = it * 256 + t;               // 0..511
            int rowl = idx >> 3, dg = (idx & 7) * 8;
            float4 f0 = *(const float4*)(T + rowl * 68 + dg);
            float4 f1 = *(const float4*)(T + rowl * 68 + dg + 4);
            uint4 o;
            o.x = pk_bf16(f0.x, f0.y);
            o.y = pk_bf16(f0.z, f0.w);
            o.z = pk_bf16(f1.x, f1.y);
            o.w = pk_bf16(f1.z, f1.w);
            int m = m0 + s * 64 + rowl;
            *(uint4*)(PA + ((size_t)(hb * N_DIM + m)) * 64 + dg) = o;
        }
    }
}

// ---------------------------------------------------------------------------
// out = g/(1+g) * (PA0 + PA1) + YP/(1+g)
// ---------------------------------------------------------------------------
__global__ __launch_bounds__(256) void combine_out(
    const short* __restrict__ PA0, const short* __restrict__ PA1,
    const float* __restrict__ YP, const float* __restrict__ gamma,
    float* __restrict__ out)
{
    size_t flat = ((size_t)blockIdx.x * 256 + threadIdx.x) * 8;
    int d  = (int)(flat & 63);
    int n  = (int)((flat >> 6) & (N_DIM - 1));
    int hb = (int)(flat >> 17);
    int h = hb >> 2, b = hb & 3;
    float g = gamma[h];
    float inv = 1.f / (1.f + g);
    float gi = g * inv;
    bf16x8 p0 = *(const bf16x8*)(PA0 + flat);
    bf16x8 p1 = *(const bf16x8*)(PA1 + flat);
    const float* yp = YP + ((size_t)b * N_DIM + n) * HD + d;
    float o[8];
#pragma unroll
    for (int j = 0; j < 8; ++j)
        o[j] = gi * (bf2f(p0[j]) + bf2f(p1[j])) + inv * yp[j];
    float4 o0 = {o[0], o[1], o[2], o[3]};
    float4 o1 = {o[4], o[5], o[6], o[7]};
    *(float4*)(out + flat) = o0;
    *(float4*)(out + flat + 4) = o1;
}

// ---------------------------------------------------------------------------
extern "C" void kernel_launch(void* const* d_in, const int* in_sizes, int n_in,
                              void* d_out, int out_size, void* d_ws, size_t ws_size,
                              hipStream_t stream) {
    const float* x     = (const float*)d_in[0];
    const float* y     = (const float*)d_in[1];
    const float* Wq    = (const float*)d_in[2];
    const float* bq    = (const float*)d_in[3];
    const float* Wk    = (const float*)d_in[4];
    const float* bk    = (const float*)d_in[5];
    const float* Wv    = (const float*)d_in[6];
    const float* bv    = (const float*)d_in[7];
    const float* Wp    = (const float*)d_in[8];
    const float* gamma = (const float*)d_in[9];
    float* out = (float*)d_out;

    const size_t XEL  = (size_t)B_DIM * C_DIM * N_DIM;  // 2,097,152
    const size_t QKV  = (size_t)HB * N_DIM * HD;        // 4,194,304

    short* XS  = (short*)d_ws;
    short* YS  = XS + XEL;
    short* WSx = YS + XEL;            // 512*256
    short* WSy = WSx + 512 * C_DIM;   // 1088*256
    short* QS  = WSy + 1088 * C_DIM;
    short* KS  = QS + QKV;
    short* VSu = KS + QKV;
    short* VS  = VSu + QKV;
    float* YPb = (float*)(VS + QKV);
    float* RSp = YPb + (size_t)B_DIM * N_DIM * HD;      // 2 * HB * N
    // overlays (dead after their producers/consumers finish):
    short* PA0 = XS;                  // XS+YS region = exactly QKV shorts
    short* PA1 = VSu;                 // VSu dead after v_scale

    dim3 blk(256);
    cast_transpose_xy<<<dim3(N_DIM / 64, C_DIM / 64, 8), blk, 0, stream>>>(x, y, XS, YS);
    cast_weights<<<dim3(200), blk, 0, stream>>>(Wq, Wk, Wv, Wp, WSx, WSy);

    proj_all<<<dim3(NTOK / 128, 25), blk, 0, stream>>>(
        WSx, WSy, XS, YS, bq, bk, bv, QS, KS, VSu, YPb);

    rowsum_mfma<<<dim3(1024), blk, 0, stream>>>(QS, KS, RSp);
    v_scale<<<dim3(2048), blk, 0, stream>>>(VSu, RSp, VS);
    attnout_mfma<<<dim3(1024), blk, 0, stream>>>(QS, KS, VS, PA0, PA1);
    combine_out<<<dim3(2048), blk, 0, stream>>>(PA0, PA1, YPb, gamma, out);
}

// Round 12
// 186.442 us; speedup vs baseline: 1.4694x; 1.0335x over previous
//
#include <hip/hip_runtime.h>
#include <math.h>

#define B_DIM 4
#define C_DIM 256
#define N_DIM 2048
#define H_DIM 8
#define HD    64
#define HB    32                 // H*B
#define NTOK  (B_DIM * N_DIM)    // 8192
#define LOG2E 1.44269504f

typedef __attribute__((ext_vector_type(8))) short bf16x8;
typedef __attribute__((ext_vector_type(4))) float f32x4;

static __device__ __forceinline__ short f2bf(float f) {          // RNE (cold paths)
    unsigned u = __builtin_bit_cast(unsigned, f);
    u += 0x7fffu + ((u >> 16) & 1u);
    return (short)(u >> 16);
}
static __device__ __forceinline__ float bf2f(short s) {
    unsigned u = ((unsigned)(unsigned short)s) << 16;
    return __builtin_bit_cast(float, u);
}
// raw v_exp_f32: exact for |x| <~ 126, skips OCML's range-guard sequence
static __device__ __forceinline__ float fx2(float x) {
#if __has_builtin(__builtin_amdgcn_exp2f)
    return __builtin_amdgcn_exp2f(x);
#else
    return exp2f(x);
#endif
}
// pack two fp32 -> two bf16 in one dword (HW packed cvt when available)
static __device__ __forceinline__ unsigned pk_bf16(float a, float b) {
#if __has_builtin(__builtin_amdgcn_cvt_pk_bf16_f32)
    auto v = __builtin_amdgcn_cvt_pk_bf16_f32(a, b);
    return __builtin_bit_cast(unsigned, v);
#else
    unsigned ua = __builtin_bit_cast(unsigned, a);
    unsigned ub = __builtin_bit_cast(unsigned, b);
    return ((ua + 0x8000u) >> 16) | ((ub + 0x8000u) & 0xffff0000u);
#endif
}

#define MFMA16(A, Bv, Cv) __builtin_amdgcn_mfma_f32_16x16x32_bf16(A, Bv, Cv, 0, 0, 0)

// Fragment-major layouts (fragment = 64 lanes x 16 B = 1 KB contiguous):
//   QS/KS(hb, rt, ks, lane, j) = M[hb][n = rt*16 + (lane&15)][d = ks*32 + (lane>>4)*8 + j]
//   (QS holds Q * log2e so exp() becomes exp2())
//   VS(hb, nb, ks, dt, lane, j) = V[hb][d = dt*16+(lane&15)][n = nb*64+ks*32+(lane>>4)*8+j]
//   XS/YS(rt, ks, lane, j) = X[tok = rt*16+(lane&15)][c = ks*32+(lane>>4)*8+j]
//   WS(ot, ks, lane, j)    = W[o  = ot*16+(lane&15)][c = ks*32+(lane>>4)*8+j]

// ---------------------------------------------------------------------------
// cast+transpose to fragment-major (z 0..7: x/y batches) + weights (z == 8)
// ---------------------------------------------------------------------------
__global__ __launch_bounds__(256) void cast_all(
    const float* __restrict__ X, const float* __restrict__ Y,
    const float* __restrict__ Wq, const float* __restrict__ Wk,
    const float* __restrict__ Wv, const float* __restrict__ Wp,
    short* __restrict__ XS, short* __restrict__ YS,
    short* __restrict__ WSx, short* __restrict__ WSy)
{
    const int z = blockIdx.z;
    const int t = threadIdx.x;

    if (z == 8) {   // ---- weights: Wq -> WSx (256 chunks); Wk|Wv|Wp -> WSy (544) ----
        int base = (blockIdx.y * 32 + blockIdx.x) * 256 + t;   // 0..32767
#pragma unroll
        for (int rep = 0; rep < 2; ++rep) {
            int gid = base + rep * 32768;                       // 0..65535
            if (gid >= 51200) break;
            int lane = gid & 63, chunk = gid >> 6;              // chunk 0..799
            int lo = lane & 15, quad = lane >> 4;
            const float* src; short* dst;
            if (chunk < 256) {
                int ot = chunk >> 3, ks = chunk & 7;
                src = Wq + (size_t)(ot * 16 + lo) * C_DIM + ks * 32 + quad * 8;
                dst = WSx + (size_t)chunk * 512 + lane * 8;
            } else {
                int ch = chunk - 256;
                int ot = ch >> 3, ks = ch & 7;
                int row = ot * 16 + lo;
                const float* basep = (row < 512) ? (Wk + (size_t)row * C_DIM)
                                   : (row < 1024) ? (Wv + (size_t)(row - 512) * C_DIM)
                                                  : (Wp + (size_t)(row - 1024) * C_DIM);
                src = basep + ks * 32 + quad * 8;
                dst = WSy + (size_t)ch * 512 + lane * 8;
            }
            bf16x8 o;
#pragma unroll
            for (int j = 0; j < 8; ++j) o[j] = f2bf(src[j]);
            *(bf16x8*)dst = o;
        }
        return;
    }

    const float* src = (z < 4) ? X : Y;
    short* dst = (z < 4) ? XS : YS;
    const int b = z & 3, c0 = blockIdx.y * 64, n0 = blockIdx.x * 64;
    __shared__ float L[64][65];   // [c_local][n_local]
    for (int i = t; i < 4096; i += 256) {
        int cc = i >> 6, nn = i & 63;
        L[cc][nn] = src[((size_t)b * C_DIM + c0 + cc) * N_DIM + n0 + nn];
    }
    __syncthreads();
#pragma unroll
    for (int half = 0; half < 2; ++half) {
        int cid = half * 256 + t;
        int lane = cid & 63, fi = cid >> 6;      // fi 0..7
        int ksl = fi & 1, rtl = fi >> 1;         // rtl 0..3
        int lo = lane & 15, quad = lane >> 4;
        bf16x8 o;
#pragma unroll
        for (int j = 0; j < 8; ++j) o[j] = f2bf(L[ksl * 32 + quad * 8 + j][rtl * 16 + lo]);
        int rt = b * 128 + (n0 >> 4) + rtl;
        int ks = (c0 >> 5) + ksl;
        *(bf16x8*)(dst + ((size_t)(rt * 8 + ks) * 64 + lane) * 8) = o;
    }
}

// ---------------------------------------------------------------------------
// Merged MFMA projection, all loads coalesced fragment loads.
// oy<8: Q=(Wq x + bq)*log2e -> QS. oy 8..15: K -> KS. oy 16..23: V -> VSu.
// oy==24: YP fp32 (b,n,d). Epilogue: LDS transpose -> coalesced 16B stores.
// ---------------------------------------------------------------------------
__global__ __launch_bounds__(256) void proj_all(
    const short* __restrict__ WSx, const short* __restrict__ WSy,
    const short* __restrict__ XS, const short* __restrict__ YS,
    const float* __restrict__ bq, const float* __restrict__ bk,
    const float* __restrict__ bv,
    short* __restrict__ QS, short* __restrict__ KS,
    short* __restrict__ VSu, float* __restrict__ Yo)
{
    const int oy = blockIdx.y;
    const bool isq = oy < 8;
    const short* WS = isq ? WSx : WSy;
    const short* Xs = isq ? XS : YS;
    const int oyl = isq ? oy : oy - 8;
    const int o0 = oyl * 64;
    const int tok0 = blockIdx.x * 128;
    const int t = threadIdx.x, wave = t >> 6, lane = t & 63;
    const int lo = lane & 15, quad = lane >> 4;

    __shared__ __align__(16) char smem[34816];

    const int ot = oyl * 4 + wave;
    const int rt0 = tok0 >> 4;
    const f32x4 czero = {0.f, 0.f, 0.f, 0.f};

    f32x4 acc[8];
#pragma unroll
    for (int i = 0; i < 8; ++i) acc[i] = czero;

#pragma unroll 2
    for (int ks = 0; ks < 8; ++ks) {
        bf16x8 a = *(const bf16x8*)(WS + ((size_t)(ot * 8 + ks) * 64 + lane) * 8);
#pragma unroll
        for (int nt = 0; nt < 8; ++nt) {
            bf16x8 bx = *(const bf16x8*)(Xs + ((size_t)((rt0 + nt) * 8 + ks) * 64 + lane) * 8);
            acc[nt] = MFMA16(a, bx, acc[nt]);
        }
    }

    const int b = tok0 >> 11;
    const int n0b = tok0 & (N_DIM - 1);

    if (oy < 16) {
        // ---- Q or K: T[128][72] bf16 -> fragment-major QS/KS ----
        short* T = (short*)smem;
        const float* bias = isq ? bq : bk;
        const float scale = isq ? LOG2E : 1.f;
        float bvr[4];
#pragma unroll
        for (int r = 0; r < 4; ++r) bvr[r] = bias[o0 + wave * 16 + quad * 4 + r];
#pragma unroll
        for (int nt = 0; nt < 8; ++nt) {
            short4 pk;
            pk.x = f2bf((acc[nt][0] + bvr[0]) * scale);
            pk.y = f2bf((acc[nt][1] + bvr[1]) * scale);
            pk.z = f2bf((acc[nt][2] + bvr[2]) * scale);
            pk.w = f2bf((acc[nt][3] + bvr[3]) * scale);
            *(short4*)(T + (nt * 16 + lo) * 72 + wave * 16 + quad * 4) = pk;
        }
        __syncthreads();
        const int h = oyl;
        const int hb = h * 4 + b;
        short* dst = isq ? QS : KS;
#pragma unroll
        for (int s = 0; s < 4; ++s) {
            int cid = s * 256 + t;
            int ln = cid & 63, fi = cid >> 6;     // fi 0..15
            int ksd = fi & 1, rtl = fi >> 1;      // rtl 0..7
            bf16x8 v = *(const bf16x8*)(T + (rtl * 16 + (ln & 15)) * 72 + ksd * 32 + (ln >> 4) * 8);
            *(bf16x8*)(dst + (((size_t)(hb * 128 + (n0b >> 4) + rtl) * 2 + ksd) * 512 + ln * 8)) = v;
        }
    } else if (oy < 24) {
        // ---- V: T2[64][136] bf16 -> fragment-major VSu ----
        short* T2 = (short*)smem;
        float bvr[4];
#pragma unroll
        for (int r = 0; r < 4; ++r) bvr[r] = bv[o0 - 512 + wave * 16 + quad * 4 + r];
#pragma unroll
        for (int nt = 0; nt < 8; ++nt)
#pragma unroll
            for (int r = 0; r < 4; ++r) {
                int ol = wave * 16 + quad * 4 + r;
                T2[ol * 136 + nt * 16 + lo] = f2bf(acc[nt][r] + bvr[r]);
            }
        __syncthreads();
        const int h = oy - 16;
        const int hb = h * 4 + b;
#pragma unroll
        for (int s = 0; s < 4; ++s) {
            int cid = s * 256 + t;
            int ln = cid & 63, fi = cid >> 6;     // fi 0..15
            int dt = fi & 3, ksd = (fi >> 2) & 1, nbl = fi >> 3;
            int dl = dt * 16 + (ln & 15);
            int tkl = nbl * 64 + ksd * 32 + (ln >> 4) * 8;
            bf16x8 v = *(const bf16x8*)(T2 + dl * 136 + tkl);
            int nbg = (n0b >> 6) + nbl;
            *(bf16x8*)(VSu + ((size_t)(((hb * 32 + nbg) * 2 + ksd) * 4 + dt) * 64 + ln) * 8) = v;
        }
    } else {
        // ---- YP: T3[128][68] fp32 -> (b,n,d) float4 stores ----
        float* T3 = (float*)smem;
#pragma unroll
        for (int nt = 0; nt < 8; ++nt) {
            float4 f;
            f.x = acc[nt][0]; f.y = acc[nt][1]; f.z = acc[nt][2]; f.w = acc[nt][3];
            *(float4*)(T3 + (nt * 16 + lo) * 68 + wave * 16 + quad * 4) = f;
        }
        __syncthreads();
#pragma unroll
        for (int s = 0; s < 8; ++s) {
            int cid = s * 256 + t;
            int row = cid >> 4, c4 = (cid & 15) * 4;
            float4 f = *(const float4*)(T3 + row * 68 + c4);
            *(float4*)(Yo + ((size_t)(tok0 + row)) * 64 + c4) = f;
        }
    }
}

// ---------------------------------------------------------------------------
// rowsum partials: RSp[z][hb][n] = sum over m-half z of exp2(Q'[n].K[m]).
// ---------------------------------------------------------------------------
__global__ __launch_bounds__(256, 4) void rowsum_mfma(
    const short* __restrict__ QS, const short* __restrict__ KS,
    float* __restrict__ RSp)
{
    const int id = blockIdx.x;
    const int hb = ((id & 7) << 2) | ((id >> 3) & 3);
    const int z = (id >> 5) & 1;
    const int n0 = (id >> 6) * 128;
    const int t = threadIdx.x, wave = t >> 6, lane = t & 63;
    const int lo = lane & 15, quad = lane >> 4;
    const f32x4 czero = {0.f, 0.f, 0.f, 0.f};

    bf16x8 a0[2], a1[2];
#pragma unroll
    for (int s = 0; s < 2; ++s) {
        int rt = (n0 >> 4) + s * 4 + wave;
        a0[s] = *(const bf16x8*)(QS + ((size_t)(hb * 128 + rt) * 2 + 0) * 512 + lane * 8);
        a1[s] = *(const bf16x8*)(QS + ((size_t)(hb * 128 + rt) * 2 + 1) * 512 + lane * 8);
    }

    float sm[2][4];
#pragma unroll
    for (int s = 0; s < 2; ++s)
#pragma unroll
        for (int r = 0; r < 4; ++r) sm[s][r] = 0.f;

    const short* kp = KS + ((size_t)(hb * 128) * 2) * 512 + lane * 8
                    + (size_t)z * (N_DIM / 2 / 16) * 2 * 512;
    for (int m0 = 0; m0 < N_DIM / 2; m0 += 64) {
#pragma unroll
        for (int mt = 0; mt < 4; ++mt) {
            bf16x8 b0 = *(const bf16x8*)(kp + (mt * 2 + 0) * 512);
            bf16x8 b1 = *(const bf16x8*)(kp + (mt * 2 + 1) * 512);
#pragma unroll
            for (int s = 0; s < 2; ++s) {
                f32x4 c = MFMA16(a0[s], b0, czero);
                c = MFMA16(a1[s], b1, c);
#pragma unroll
                for (int r = 0; r < 4; ++r) sm[s][r] += fx2(c[r]);
            }
        }
        kp += 8 * 512;
    }

#pragma unroll
    for (int sft = 1; sft < 16; sft <<= 1)
#pragma unroll
        for (int s = 0; s < 2; ++s)
#pragma unroll
            for (int r = 0; r < 4; ++r) sm[s][r] += __shfl_xor(sm[s][r], sft);

    if (lo == 0) {
#pragma unroll
        for (int s = 0; s < 2; ++s) {
            int row = n0 + s * 64 + wave * 16 + quad * 4;
#pragma unroll
            for (int r = 0; r < 4; ++r)
                RSp[((size_t)z * HB + hb) * N_DIM + row + r] = sm[s][r];
        }
    }
}

// ---------------------------------------------------------------------------
// VS = VSu * 1/(RSp0[n]+RSp1[n]) — same fragment-major layout in and out
// ---------------------------------------------------------------------------
__global__ __launch_bounds__(256) void v_scale(
    const short* __restrict__ VSu, const float* __restrict__ RSp,
    short* __restrict__ VS)
{
    int t = blockIdx.x * 256 + threadIdx.x;     // 0..524287
    int lane = t & 63, fidx = t >> 6;
    int ks = (fidx >> 2) & 1, nb = (fidx >> 3) & 31, hb = fidx >> 8;
    int n = nb * 64 + ks * 32 + (lane >> 4) * 8;
    bf16x8 v = *(const bf16x8*)(VSu + (size_t)t * 8);
    const float* r0 = RSp + (size_t)hb * N_DIM + n;
    const float* r1 = r0 + (size_t)HB * N_DIM;
    bf16x8 o;
#pragma unroll
    for (int j = 0; j < 8; ++j) o[j] = f2bf(bf2f(v[j]) / (r0[j] + r1[j]));
    *(bf16x8*)(VS + (size_t)t * 8) = o;
}

// ---------------------------------------------------------------------------
// attnout: PA_z[hb,m,d] (bf16) = sum_{n in half z} exp2(Q'.K) Vsc[n,d]
// 128-m tile x n-half. 1024 blocks. Software-pipelined K-loop:
//   iter i: [load Q(i+1)] [expwrite(i)] [QK-MFMA(i+1)] [PV(i)]
// so the LDS write->read pair and global-load->use pairs are separated by
// independent MFMA/exp work. Single per-wave Pl buffer (in-order DS queue).
// ---------------------------------------------------------------------------
__global__ __launch_bounds__(256, 4) void attnout_mfma(
    const short* __restrict__ QS, const short* __restrict__ KS,
    const short* __restrict__ VS,
    short* __restrict__ PA0, short* __restrict__ PA1)
{
    const int id = blockIdx.x;
    const int hb = ((id & 7) << 2) | ((id >> 3) & 3);
    const int z = (id >> 5) & 1;
    const int m0 = (id >> 6) * 128;

    __shared__ __align__(16) char smem[17408];   // Pl (16 KB) / epilogue T (17.4 KB)
    short* Pl = (short*)smem;

    const int t = threadIdx.x, wave = t >> 6, lane = t & 63;
    const int lo = lane & 15, quad = lane >> 4;
    const f32x4 czero = {0.f, 0.f, 0.f, 0.f};

    bf16x8 bk0[2], bk1[2];
#pragma unroll
    for (int s = 0; s < 2; ++s) {
        int rt = (m0 >> 4) + s * 4 + wave;
        bk0[s] = *(const bf16x8*)(KS + ((size_t)(hb * 128 + rt) * 2 + 0) * 512 + lane * 8);
        bk1[s] = *(const bf16x8*)(KS + ((size_t)(hb * 128 + rt) * 2 + 1) * 512 + lane * 8);
    }

    f32x4 oacc[2][4];
#pragma unroll
    for (int s = 0; s < 2; ++s)
#pragma unroll
        for (int dt = 0; dt < 4; ++dt) oacc[s][dt] = czero;

    const short* qp = QS + ((size_t)(hb * 128) * 2) * 512 + lane * 8
                    + (size_t)z * (N_DIM / 2 / 16) * 2 * 512;
    const short* vp = VS + ((size_t)(hb * 32) * 8) * 512 + lane * 8
                    + (size_t)z * (N_DIM / 2 / 64) * 8 * 512;
    short* prowA = Pl + (wave * 16 + lo) * 64;
    short* prowB = prowA + 64 * 64;
    const int lh = lo & 7;
    const int NIT = N_DIM / 2 / 64;   // 16

    f32x4 c[4][2];                    // E' results for the "current" iteration

    // ---- prologue: QK(0) ----
    {
#pragma unroll
        for (int nt = 0; nt < 4; ++nt) {
            bf16x8 a0 = *(const bf16x8*)(qp + (nt * 2 + 0) * 512);
            bf16x8 a1 = *(const bf16x8*)(qp + (nt * 2 + 1) * 512);
#pragma unroll
            for (int s = 0; s < 2; ++s) {
                c[nt][s] = MFMA16(a0, bk0[s], czero);
                c[nt][s] = MFMA16(a1, bk1[s], c[nt][s]);
            }
        }
        qp += 8 * 512;
    }

    for (int i = 0; i < NIT - 1; ++i) {
        // ---- load Q fragments for iter i+1 (use separated by exp chain) ----
        bf16x8 a0[4], a1[4];
#pragma unroll
        for (int nt = 0; nt < 4; ++nt) {
            a0[nt] = *(const bf16x8*)(qp + (nt * 2 + 0) * 512);
            a1[nt] = *(const bf16x8*)(qp + (nt * 2 + 1) * 512);
        }
        // ---- expwrite(i): P = exp2(E') -> Pl ----
#pragma unroll
        for (int nt = 0; nt < 4; ++nt)
#pragma unroll
            for (int s = 0; s < 2; ++s) {
                uint2 pk;
                pk.x = pk_bf16(fx2(c[nt][s][0]), fx2(c[nt][s][1]));
                pk.y = pk_bf16(fx2(c[nt][s][2]), fx2(c[nt][s][3]));
                int chunk = nt * 2 + (quad >> 1);
                *(uint2*)((s ? prowB : prowA) + (((chunk ^ lh) << 3) | ((quad & 1) << 2))) = pk;
            }
        // ---- QK-MFMA(i+1) (separates ds_write(i) from ds_read(i)) ----
#pragma unroll
        for (int nt = 0; nt < 4; ++nt)
#pragma unroll
            for (int s = 0; s < 2; ++s) {
                c[nt][s] = MFMA16(a0[nt], bk0[s], czero);
                c[nt][s] = MFMA16(a1[nt], bk1[s], c[nt][s]);
            }
        // ---- PV(i) ----
#pragma unroll
        for (int ks = 0; ks < 2; ++ks) {
            bf16x8 ap0 = *(const bf16x8*)(prowA + (((ks * 4 + quad) ^ lh) << 3));
            bf16x8 ap1 = *(const bf16x8*)(prowB + (((ks * 4 + quad) ^ lh) << 3));
#pragma unroll
            for (int dt = 0; dt < 4; ++dt) {
                bf16x8 bv = *(const bf16x8*)(vp + (ks * 4 + dt) * 512);
                oacc[0][dt] = MFMA16(ap0, bv, oacc[0][dt]);
                oacc[1][dt] = MFMA16(ap1, bv, oacc[1][dt]);
            }
        }
        qp += 8 * 512;
        vp += 8 * 512;
    }

    // ---- tail: expwrite(NIT-1) + PV(NIT-1) ----
#pragma unroll
    for (int nt = 0; nt < 4; ++nt)
#pragma unroll
        for (int s = 0; s < 2; ++s) {
            uint2 pk;
            pk.x = pk_bf16(fx2(c[nt][s][0]), fx2(c[nt][s][1]));
            pk.y = pk_bf16(fx2(c[nt][s][2]), fx2(c[nt][s][3]));
            int chunk = nt * 2 + (quad >> 1);
            *(uint2*)((s ? prowB : prowA) + (((chunk ^ lh) << 3) | ((quad & 1) << 2))) = pk;
        }
#pragma unroll
    for (int ks = 0; ks < 2; ++ks) {
        bf16x8 ap0 = *(const bf16x8*)(prowA + (((ks * 4 + quad) ^ lh) << 3));
        bf16x8 ap1 = *(const bf16x8*)(prowB + (((ks * 4 + quad) ^ lh) << 3));
#pragma unroll
        for (int dt = 0; dt < 4; ++dt) {
            bf16x8 bv = *(const bf16x8*)(vp + (ks * 4 + dt) * 512);
            oacc[0][dt] = MFMA16(ap0, bv, oacc[0][dt]);
            oacc[1][dt] = MFMA16(ap1, bv, oacc[1][dt]);
        }
    }

    // ---- epilogue: LDS transpose -> coalesced bf16 partial stores ----
    short* PA = z ? PA1 : PA0;
    float* T = (float*)smem;                      // [64][68]
#pragma unroll
    for (int s = 0; s < 2; ++s) {
        __syncthreads();                          // Pl / previous T reads done
#pragma unroll
        for (int dt = 0; dt < 4; ++dt)
#pragma unroll
            for (int r = 0; r < 4; ++r)
                T[(wave * 16 + quad * 4 + r) * 68 + dt * 16 + lo] = oacc[s][dt][r];
        __syncthreads();
#pragma unroll
        for (int it = 0; it < 2; ++it) {
            int idx = it * 256 + t;               // 0..511
            int rowl = idx >> 3, dg = (idx & 7) * 8;
            float4 f0 = *(const float4*)(T + rowl * 68 + dg);
            float4 f1 = *(const float4*)(T + rowl * 68 + dg + 4);
            uint4 o;
            o.x = pk_bf16(f0.x, f0.y);
            o.y = pk_bf16(f0.z, f0.w);
            o.z = pk_bf16(f1.x, f1.y);
            o.w = pk_bf16(f1.z, f1.w);
            int m = m0 + s * 64 + rowl;
            *(uint4*)(PA + ((size_t)(hb * N_DIM + m)) * 64 + dg) = o;
        }
    }
}

// ---------------------------------------------------------------------------
// out = g/(1+g) * (PA0 + PA1) + YP/(1+g)
// ---------------------------------------------------------------------------
__global__ __launch_bounds__(256) void combine_out(
    const short* __restrict__ PA0, const short* __restrict__ PA1,
    const float* __restrict__ YP, const float* __restrict__ gamma,
    float* __restrict__ out)
{
    size_t flat = ((size_t)blockIdx.x * 256 + threadIdx.x) * 8;
    int d  = (int)(flat & 63);
    int n  = (int)((flat >> 6) & (N_DIM - 1));
    int hb = (int)(flat >> 17);
    int h = hb >> 2, b = hb & 3;
    float g = gamma[h];
    float inv = 1.f / (1.f + g);
    float gi = g * inv;
    bf16x8 p0 = *(const bf16x8*)(PA0 + flat);
    bf16x8 p1 = *(const bf16x8*)(PA1 + flat);
    const float* yp = YP + ((size_t)b * N_DIM + n) * HD + d;
    float o[8];
#pragma unroll
    for (int j = 0; j < 8; ++j)
        o[j] = gi * (bf2f(p0[j]) + bf2f(p1[j])) + inv * yp[j];
    float4 o0 = {o[0], o[1], o[2], o[3]};
    float4 o1 = {o[4], o[5], o[6], o[7]};
    *(float4*)(out + flat) = o0;
    *(float4*)(out + flat + 4) = o1;
}

// ---------------------------------------------------------------------------
extern "C" void kernel_launch(void* const* d_in, const int* in_sizes, int n_in,
                              void* d_out, int out_size, void* d_ws, size_t ws_size,
                              hipStream_t stream) {
    const float* x     = (const float*)d_in[0];
    const float* y     = (const float*)d_in[1];
    const float* Wq    = (const float*)d_in[2];
    const float* bq    = (const float*)d_in[3];
    const float* Wk    = (const float*)d_in[4];
    const float* bk    = (const float*)d_in[5];
    const float* Wv    = (const float*)d_in[6];
    const float* bv    = (const float*)d_in[7];
    const float* Wp    = (const float*)d_in[8];
    const float* gamma = (const float*)d_in[9];
    float* out = (float*)d_out;

    const size_t XEL  = (size_t)B_DIM * C_DIM * N_DIM;  // 2,097,152
    const size_t QKV  = (size_t)HB * N_DIM * HD;        // 4,194,304

    short* XS  = (short*)d_ws;
    short* YS  = XS + XEL;
    short* WSx = YS + XEL;            // 512*256
    short* WSy = WSx + 512 * C_DIM;   // 1088*256
    short* QS  = WSy + 1088 * C_DIM;
    short* KS  = QS + QKV;
    short* VSu = KS + QKV;
    short* VS  = VSu + QKV;
    float* YPb = (float*)(VS + QKV);
    float* RSp = YPb + (size_t)B_DIM * N_DIM * HD;      // 2 * HB * N
    // overlays (dead after their producers/consumers finish):
    short* PA0 = XS;                  // XS+YS region = exactly QKV shorts
    short* PA1 = VSu;                 // VSu dead after v_scale

    dim3 blk(256);
    cast_all<<<dim3(N_DIM / 64, C_DIM / 64, 9), blk, 0, stream>>>(
        x, y, Wq, Wk, Wv, Wp, XS, YS, WSx, WSy);

    proj_all<<<dim3(NTOK / 128, 25), blk, 0, stream>>>(
        WSx, WSy, XS, YS, bq, bk, bv, QS, KS, VSu, YPb);

    rowsum_mfma<<<dim3(1024), blk, 0, stream>>>(QS, KS, RSp);
    v_scale<<<dim3(2048), blk, 0, stream>>>(VSu, RSp, VS);
    attnout_mfma<<<dim3(1024), blk, 0, stream>>>(QS, KS, VS, PA0, PA1);
    combine_out<<<dim3(2048), blk, 0, stream>>>(PA0, PA1, YPb, gamma, out);
}